// Round 15
// baseline (432.752 us; speedup 1.0000x reference)
//
#include <hip/hip_runtime.h>

// GIN encoder: N=100k, E=3.2M, G=512, H=64, L=3.
// Round 15: full layer fusion. gin_layer<L0> (782 blocks, 1 bucket = 128
// nodes each): phase1 = agg64_bn-style gather (+BN+ReLU of prev layer) into
// an 18KB LDS activation tile (MFMA-A layout, stride 72 shorts); phase2 =
// two 64-row MFMA tiles from LDS (weights hoisted to registers), coalesced
// LDS-staged epilogue, BN partials to private global slots. Eliminates 3
// standalone mlp launches (~32us each at 1% MfmaUtil) + 2x25.6MB of
// intermediate traffic. bn_reduce v2 (64 blocks), scatter_sort,
// bucket_csr v3, bn_pool_out unchanged from R14 (377us).

#define NBMAX 1024
#define CAP 4608
#define CHUNK 8192
#define NBLK_MAX 512
#define MSTR 72   // LDS row stride in shorts (9 uint4, bank-staggered)

typedef __attribute__((ext_vector_type(8))) short bf16x8;
typedef __attribute__((ext_vector_type(4))) float f32x4;

static __device__ __forceinline__ bf16x8 as_bf16x8(uint4 u) {
    union { uint4 a; bf16x8 b; } x; x.a = u; return x.b;
}
static __device__ __forceinline__ unsigned short bf16r(float v) {
    unsigned u = __float_as_uint(v);
    return (unsigned short)((u + 0x7FFFu + ((u >> 16) & 1u)) >> 16);
}
static __device__ __forceinline__ unsigned bf16pack2(float a, float b) {
    return (unsigned)bf16r(a) | ((unsigned)bf16r(b) << 16);
}

// ---- weight prep: bf16, transposed to [col][k] ----
__global__ void prep_weights(const float* __restrict__ w1_0, const float* __restrict__ w1_r,
                             const float* __restrict__ w2, unsigned short* __restrict__ w1T0,
                             unsigned short* __restrict__ w1T, unsigned short* __restrict__ w2T) {
    int t = blockIdx.x * 256 + threadIdx.x;
    if (t < 64 * 32) {
        int c = t >> 5, k = t & 31;
        w1T0[t] = bf16r(k < 3 ? w1_0[k * 64 + c] : 0.f);
    }
    if (t < 2 * 64 * 64) {
        int l = t >> 12, r = t & 4095, c = r >> 6, k = r & 63;
        w1T[t] = bf16r(w1_r[l * 4096 + k * 64 + c]);
    }
    if (t < 3 * 64 * 64) {
        int l = t >> 12, r = t & 4095, c = r >> 6, k = r & 63;
        w2T[t] = bf16r(w2[l * 4096 + k * 64 + c]);
    }
}

// ---- scatter_sort: block counting-sorts its 8192-edge chunk by bucket ----
__global__ __launch_bounds__(512) void scatter_sort(
    const int* __restrict__ src, const int* __restrict__ dst,
    int* __restrict__ bucketed2, int* __restrict__ offsTab, int E) {
    __shared__ int hist[NBMAX];
    __shared__ int offs[NBMAX];
    __shared__ int stage[CHUNK];
    int t = threadIdx.x, blk = blockIdx.x;
    int e0 = blk * CHUNK, e1 = min(e0 + CHUNK, E);
    int len = e1 - e0;
    hist[t] = 0; hist[t + 512] = 0;
    __syncthreads();
    for (int e = e0 + t; e < e1; e += 512) atomicAdd(&hist[dst[e] >> 7], 1);
    __syncthreads();
    offs[t] = hist[t]; offs[t + 512] = hist[t + 512];
    __syncthreads();
    for (int off = 1; off < 1024; off <<= 1) {
        int v0 = (t >= off) ? offs[t - off] : 0;
        int v1 = offs[t + 512 - off];
        __syncthreads();
        offs[t] += v0;
        offs[t + 512] += v1;
        __syncthreads();
    }
    offs[t] -= hist[t]; offs[t + 512] -= hist[t + 512];
    hist[t] = 0; hist[t + 512] = 0;
    __syncthreads();
    offsTab[blk * 1025 + t] = offs[t];
    offsTab[blk * 1025 + t + 512] = offs[t + 512];
    if (t == 0) offsTab[blk * 1025 + 1024] = len;
    for (int e = e0 + t; e < e1; e += 512) {
        int d = dst[e];
        int bk = d >> 7;
        int r = offs[bk] + atomicAdd(&hist[bk], 1);
        stage[r] = src[e] | ((d & 127) << 20);
    }
    __syncthreads();
    for (int j = t; j < len; j += 512) bucketed2[e0 + j] = stage[j];
}

// ---- bucket_csr v3: binsearch run-gather, counting sort by src-block, then
// by row -> CSR with ~src-ascending rows (L2 locality for agg) ----
__global__ __launch_bounds__(256) void bucket_csr(
    const int* __restrict__ bucketed2, const int* __restrict__ offsTab,
    int* __restrict__ csrOut, int* __restrict__ rowstart, int* __restrict__ rowend,
    int N, int nblk) {
    __shared__ int ein[CAP];
    __shared__ int emid[CAP];
    __shared__ int runs[NBLK_MAX];
    __shared__ int rbeg[NBLK_MAX];
    __shared__ int hist[128];
    __shared__ int base[129];
    int b = blockIdx.x, t = threadIdx.x, node0 = b << 7;
    for (int r = t; r < NBLK_MAX; r += 256) {
        int l = 0, g0 = 0;
        if (r < nblk) {
            int beg = offsTab[r * 1025 + b];
            int end = offsTab[r * 1025 + b + 1];
            l = end - beg;
            g0 = r * CHUNK + beg;
        }
        runs[r] = l;
        rbeg[r] = g0;
    }
    __syncthreads();
    for (int off = 1; off < NBLK_MAX; off <<= 1) {
        int v0 = (t >= off) ? runs[t - off] : 0;
        int v1 = (t + 256 >= off) ? runs[t + 256 - off] : 0;
        __syncthreads();
        runs[t] += v0;
        runs[t + 256] += v1;
        __syncthreads();
    }
    int cnt = min(runs[NBLK_MAX - 1], CAP);
    for (int j = t; j < cnt; j += 256) {
        int lo = 0, hi = nblk - 1;
        while (lo < hi) {
            int m = (lo + hi) >> 1;
            if (runs[m] > j) hi = m; else lo = m + 1;
        }
        int st = lo ? runs[lo - 1] : 0;
        ein[j] = bucketed2[rbeg[lo] + (j - st)];
    }
    // pass 1: group by src block (src>>10)
    if (t < 128) hist[t] = 0;
    __syncthreads();
    for (int j = t; j < cnt; j += 256) atomicAdd(&hist[(ein[j] & 0xFFFFF) >> 10], 1);
    __syncthreads();
    if (t < 128) base[t + 1] = hist[t];
    if (t == 0) base[0] = 0;
    __syncthreads();
    for (int off = 1; off < 128; off <<= 1) {
        int v = 0;
        if (t < 128 && (t + 1) > off) v = base[t + 1 - off];
        __syncthreads();
        if (t < 128 && (t + 1) > off) base[t + 1] += v;
        __syncthreads();
    }
    if (t < 128) hist[t] = 0;
    __syncthreads();
    for (int j = t; j < cnt; j += 256) {
        int p = ein[j];
        int sb = (p & 0xFFFFF) >> 10;
        int pos = base[sb] + atomicAdd(&hist[sb], 1);
        emid[pos] = p;
    }
    __syncthreads();
    // pass 2: counting sort by row
    if (t < 128) hist[t] = 0;
    __syncthreads();
    for (int j = t; j < cnt; j += 256) atomicAdd(&hist[emid[j] >> 20], 1);
    __syncthreads();
    if (t < 128) base[t + 1] = hist[t];
    if (t == 0) base[0] = 0;
    __syncthreads();
    for (int off = 1; off < 128; off <<= 1) {
        int v = 0;
        if (t < 128 && (t + 1) > off) v = base[t + 1 - off];
        __syncthreads();
        if (t < 128 && (t + 1) > off) base[t + 1] += v;
        __syncthreads();
    }
    if (t < 128) {
        int n = node0 + t;
        if (n < N) {
            rowstart[n] = b * CAP + base[t];
            rowend[n] = b * CAP + base[t + 1];
        }
        hist[t] = 0;
    }
    __syncthreads();
    for (int j = t; j < cnt; j += 256) {
        int p = emid[j];
        int local = p >> 20;
        int pos = base[local] + atomicAdd(&hist[local], 1);
        ein[pos] = p & 0xFFFFF;
    }
    __syncthreads();
    for (int j = t; j < cnt; j += 256) csrOut[b * CAP + j] = ein[j];
}

// bf16x2-packed accumulate of relu(v*sc+sh)
__device__ __forceinline__ void accum_bf16(const uint4 u,
                                           const float4 scA, const float4 scB,
                                           const float4 shA, const float4 shB,
                                           float* __restrict__ a) {
    a[0] += fmaxf(__uint_as_float(u.x << 16) * scA.x + shA.x, 0.f);
    a[1] += fmaxf(__uint_as_float(u.x & 0xFFFF0000u) * scA.y + shA.y, 0.f);
    a[2] += fmaxf(__uint_as_float(u.y << 16) * scA.z + shA.z, 0.f);
    a[3] += fmaxf(__uint_as_float(u.y & 0xFFFF0000u) * scA.w + shA.w, 0.f);
    a[4] += fmaxf(__uint_as_float(u.z << 16) * scB.x + shB.x, 0.f);
    a[5] += fmaxf(__uint_as_float(u.z & 0xFFFF0000u) * scB.y + shB.y, 0.f);
    a[6] += fmaxf(__uint_as_float(u.w << 16) * scB.z + shB.z, 0.f);
    a[7] += fmaxf(__uint_as_float(u.w & 0xFFFF0000u) * scB.w + shB.w, 0.f);
}

// ---- fused GIN layer: one block per 128-node bucket.
// phase1: gather (+prev BN+ReLU) -> LDS acts tile; phase2: 2x MFMA MLP tiles
// from LDS; coalesced bf16 output; BN partials -> private slots. ----
template <bool L0>
__global__ __launch_bounds__(256) void gin_layer(
    const void* __restrict__ actInRaw,      // L0: float* x (d=3); else ushort* h
    const int* __restrict__ rowstart, const int* __restrict__ rowend,
    const int* __restrict__ csr,
    const float* __restrict__ bnsumPrev, const float* __restrict__ bnsqPrev,
    const float* __restrict__ gammaPrev, const float* __restrict__ betaPrev,
    const uint4* __restrict__ w1Tu, const float* __restrict__ b1,
    const uint4* __restrict__ w2Tu, const float* __restrict__ b2,
    uint4* __restrict__ houtU4,
    float* __restrict__ partS, float* __restrict__ partQ, int N) {
    __shared__ __align__(16) unsigned short acts[128 * MSTR];  // 18KB
    __shared__ __align__(16) unsigned short mids[64 * MSTR];   // 9KB
    __shared__ float red[16][64];
    __shared__ float scs[64], shs[64];
    int t = threadIdx.x;
    int b = blockIdx.x, node0 = b << 7;
    const uint4 z4 = make_uint4(0, 0, 0, 0);
    uint4* actsU4 = (uint4*)acts;

    if (!L0) {
        if (t < 64) {
            float mu = bnsumPrev[t] / (float)N;
            float var = bnsqPrev[t] / (float)N - mu * mu;
            float s = gammaPrev[t] * rsqrtf(var + 1e-5f);
            scs[t] = s;
            shs[t] = betaPrev[t] - mu * s;
        }
        __syncthreads();
    }

    // ---- phase 1: gather into acts ----
    if (L0) {
        const float* x = (const float*)actInRaw;
        if (t < 128) {
            int n = node0 + t;
            float s0 = 0.f, s1 = 0.f, s2 = 0.f;
            if (n < N) {
                s0 = x[n * 3]; s1 = x[n * 3 + 1]; s2 = x[n * 3 + 2];
                float b0 = 0.f, b1v = 0.f, b2v = 0.f;
                float c0 = 0.f, c1 = 0.f, c2 = 0.f;
                float d0 = 0.f, d1 = 0.f, d2 = 0.f;
                int s = rowstart[n], e = rowend[n];
                int j = s;
                for (; j + 3 < e; j += 4) {
                    int i0 = csr[j], i1 = csr[j + 1], i2 = csr[j + 2], i3 = csr[j + 3];
                    s0 += x[i0 * 3]; s1 += x[i0 * 3 + 1]; s2 += x[i0 * 3 + 2];
                    b0 += x[i1 * 3]; b1v += x[i1 * 3 + 1]; b2v += x[i1 * 3 + 2];
                    c0 += x[i2 * 3]; c1 += x[i2 * 3 + 1]; c2 += x[i2 * 3 + 2];
                    d0 += x[i3 * 3]; d1 += x[i3 * 3 + 1]; d2 += x[i3 * 3 + 2];
                }
                for (; j < e; j++) {
                    int nb = csr[j];
                    s0 += x[nb * 3]; s1 += x[nb * 3 + 1]; s2 += x[nb * 3 + 2];
                }
                s0 += b0 + c0 + d0; s1 += b1v + c1 + d1; s2 += b2v + c2 + d2;
            }
            actsU4[t * 9] = make_uint4(bf16pack2(s0, s1), bf16pack2(s2, 0.f), 0u, 0u);
        }
    } else {
        const uint4* hr = (const uint4*)actInRaw;
        int g = t >> 3, l = t & 7;
        int c0i = l * 8;
        float4 scA = *(const float4*)&scs[c0i], scB = *(const float4*)&scs[c0i + 4];
        float4 shA = *(const float4*)&shs[c0i], shB = *(const float4*)&shs[c0i + 4];
        for (int p = 0; p < 4; p++) {
            int r = p * 32 + g;
            int n = node0 + r;
            float A[8] = {0,0,0,0,0,0,0,0};
            float B[8] = {0,0,0,0,0,0,0,0};
            if (n < N) {
                accum_bf16(hr[(size_t)n * 8 + l], scA, scB, shA, shB, A);  // self
                int s = rowstart[n], e = rowend[n];
                int j = s;
                for (; j + 3 < e; j += 4) {
                    int i0 = csr[j], i1 = csr[j + 1], i2 = csr[j + 2], i3 = csr[j + 3];
                    uint4 w0 = hr[(size_t)i0 * 8 + l];
                    uint4 w1 = hr[(size_t)i1 * 8 + l];
                    uint4 w2 = hr[(size_t)i2 * 8 + l];
                    uint4 w3 = hr[(size_t)i3 * 8 + l];
                    accum_bf16(w0, scA, scB, shA, shB, A);
                    accum_bf16(w1, scA, scB, shA, shB, B);
                    accum_bf16(w2, scA, scB, shA, shB, A);
                    accum_bf16(w3, scA, scB, shA, shB, B);
                }
                for (; j < e; j++) {
                    uint4 w = hr[(size_t)csr[j] * 8 + l];
                    accum_bf16(w, scA, scB, shA, shB, A);
                }
            }
            uint4 o;
            o.x = bf16pack2(A[0] + B[0], A[1] + B[1]);
            o.y = bf16pack2(A[2] + B[2], A[3] + B[3]);
            o.z = bf16pack2(A[4] + B[4], A[5] + B[5]);
            o.w = bf16pack2(A[6] + B[6], A[7] + B[7]);
            actsU4[r * 9 + l] = o;
        }
    }

    // ---- phase 2: MLP via MFMA, 2 tiles of 64 rows ----
    int w = t >> 6, l64 = t & 63;
    int m16 = l64 & 15, q = l64 >> 4;
    bf16x8 w1f[4][2], w2f[4][2];
    float bias1[4], bias2[4];
#pragma unroll
    for (int c = 0; c < 4; c++) {
        int col = c * 16 + m16;
        if (L0) {
            w1f[c][0] = as_bf16x8(w1Tu[col * 4 + q]);
        } else {
            w1f[c][0] = as_bf16x8(w1Tu[col * 8 + q]);
            w1f[c][1] = as_bf16x8(w1Tu[col * 8 + 4 + q]);
        }
        w2f[c][0] = as_bf16x8(w2Tu[col * 8 + q]);
        w2f[c][1] = as_bf16x8(w2Tu[col * 8 + 4 + q]);
        bias1[c] = b1[col];
        bias2[c] = b2[col];
    }
    float s[4] = {0, 0, 0, 0}, sq[4] = {0, 0, 0, 0};
    const uint4* midU4 = (const uint4*)mids;
    for (int T = 0; T < 2; T++) {
        __syncthreads();  // acts ready (T=0) / mids store done (T=1)
        int rloc = T * 64 + w * 16 + m16;
        bf16x8 a0, a1;
        if (L0) {
            a0 = as_bf16x8(q == 0 ? actsU4[rloc * 9] : z4);
        } else {
            a0 = as_bf16x8(actsU4[rloc * 9 + q]);
            a1 = as_bf16x8(actsU4[rloc * 9 + 4 + q]);
        }
#pragma unroll
        for (int c = 0; c < 4; c++) {
            float bias = bias1[c];
            f32x4 acc = {bias, bias, bias, bias};
            if (L0) {
                acc = __builtin_amdgcn_mfma_f32_16x16x32_bf16(a0, w1f[c][0], acc, 0, 0, 0);
            } else {
                acc = __builtin_amdgcn_mfma_f32_16x16x32_bf16(a0, w1f[c][0], acc, 0, 0, 0);
                acc = __builtin_amdgcn_mfma_f32_16x16x32_bf16(a1, w1f[c][1], acc, 0, 0, 0);
            }
            int col = c * 16 + m16;
#pragma unroll
            for (int r = 0; r < 4; r++) {
                int row = w * 16 + q * 4 + r;
                mids[row * MSTR + col] = bf16r(fmaxf(acc[r], 0.f));
            }
        }
        __syncthreads();
        int rowM = w * 16 + m16;
        bf16x8 a20 = as_bf16x8(midU4[rowM * 9 + q]);
        bf16x8 a21 = as_bf16x8(midU4[rowM * 9 + 4 + q]);
        f32x4 accs[4];
#pragma unroll
        for (int c = 0; c < 4; c++) {
            float bias = bias2[c];
            f32x4 acc = {bias, bias, bias, bias};
            acc = __builtin_amdgcn_mfma_f32_16x16x32_bf16(a20, w2f[c][0], acc, 0, 0, 0);
            acc = __builtin_amdgcn_mfma_f32_16x16x32_bf16(a21, w2f[c][1], acc, 0, 0, 0);
            accs[c] = acc;
        }
        __syncthreads();  // all mids reads done -> reuse as output staging
#pragma unroll
        for (int c = 0; c < 4; c++) {
            int col = c * 16 + m16;
#pragma unroll
            for (int r = 0; r < 4; r++) {
                int row = w * 16 + q * 4 + r;
                float v = accs[c][r];
                if (node0 + T * 64 + row < N) { s[c] += v; sq[c] += v * v; }
                mids[row * MSTR + col] = bf16r(v);
            }
        }
        __syncthreads();
        // coalesced store: 64 rows x 8 uint4
        int tbase = node0 + T * 64;
        for (int i = t; i < 512; i += 256) {
            int row = i >> 3, qo = i & 7;
            int gr = tbase + row;
            if (gr < N) houtU4[(size_t)gr * 8 + qo] = midU4[row * 9 + qo];
        }
    }
    // BN partial reduce -> private global slot
    __syncthreads();
    for (int c = 0; c < 4; c++) red[w * 4 + q][c * 16 + m16] = s[c];
    __syncthreads();
    if (t < 64) {
        float S = 0.f;
        for (int i = 0; i < 16; i++) S += red[i][t];
        partS[b * 64 + t] = S;
    }
    __syncthreads();
    for (int c = 0; c < 4; c++) red[w * 4 + q][c * 16 + m16] = sq[c];
    __syncthreads();
    if (t < 64) {
        float S = 0.f;
        for (int i = 0; i < 16; i++) S += red[i][t];
        partQ[b * 64 + t] = S;
    }
}

// ---- bn_reduce v2: 64 blocks, block b reduces column b over nParts ----
__global__ __launch_bounds__(256) void bn_reduce(
    const float* __restrict__ partS, const float* __restrict__ partQ,
    float* __restrict__ bnsum, float* __restrict__ bnsq, int nParts) {
    __shared__ float rs[256], rq[256];
    int b = blockIdx.x, t = threadIdx.x;
    float S = 0.f, Q = 0.f;
    for (int p = t; p < nParts; p += 256) {
        S += partS[p * 64 + b];
        Q += partQ[p * 64 + b];
    }
    rs[t] = S; rq[t] = Q;
    __syncthreads();
    for (int off = 128; off > 0; off >>= 1) {
        if (t < off) { rs[t] += rs[t + off]; rq[t] += rq[t + off]; }
        __syncthreads();
    }
    if (t == 0) { bnsum[b] = rs[0]; bnsq[b] = rq[0]; }
}

// ---- BN apply + mean-pool + output matmul (batch sorted; zero atomics) ----
__device__ __forceinline__ int lowb(const int* __restrict__ a, int n, int v) {
    int lo = 0, hi = n;
    while (lo < hi) {
        int m = (lo + hi) >> 1;
        if (a[m] < v) lo = m + 1; else hi = m;
    }
    return lo;
}

__global__ __launch_bounds__(256) void bn_pool_out(
    const unsigned short* __restrict__ h, const int* __restrict__ batch,
    const float* __restrict__ bnsum, const float* __restrict__ bnsq,
    const float* __restrict__ gamma, const float* __restrict__ beta,
    const float* __restrict__ wout, const float* __restrict__ bout,
    float* __restrict__ out, int N) {
    __shared__ float sc[64], sh[64];
    __shared__ float part[4][64];
    __shared__ float gr[64];
    __shared__ int range[2];
    int g = blockIdx.x, t = threadIdx.x;
    if (t < 64) {
        float mu = bnsum[t] / (float)N;
        float var = bnsq[t] / (float)N - mu * mu;
        float s = gamma[t] * rsqrtf(var + 1e-5f);
        sc[t] = s;
        sh[t] = beta[t] - mu * s;
    }
    if (t == 64) range[0] = lowb(batch, N, g);
    if (t == 65) range[1] = lowb(batch, N, g + 1);
    __syncthreads();
    int s0 = range[0], s1 = range[1];
    int col = t & 63, ro = t >> 6;
    float acc = 0.f;
    for (int n = s0 + ro; n < s1; n += 4) {
        float v = __uint_as_float(((unsigned)h[(size_t)n * 64 + col]) << 16);
        acc += fmaxf(v * sc[col] + sh[col], 0.f);
    }
    part[ro][col] = acc;
    __syncthreads();
    if (t < 64) {
        float S = part[0][t] + part[1][t] + part[2][t] + part[3][t];
        float c = (float)(s1 - s0);
        gr[t] = (c > 0.f) ? S / c : 0.f;
    }
    __syncthreads();
    if (t < 64) {
        float a = bout[t];
        for (int f = 0; f < 64; f++) a += gr[f] * wout[f * 64 + t];
        out[g * 64 + t] = a;
    }
}

extern "C" void kernel_launch(void* const* d_in, const int* in_sizes, int n_in,
                              void* d_out, int out_size, void* d_ws, size_t ws_size,
                              hipStream_t stream) {
    const float* x     = (const float*)d_in[0];
    const int*   ei    = (const int*)d_in[1];
    const int*   batch = (const int*)d_in[2];
    const float* w1_0  = (const float*)d_in[3];
    const float* w1_r  = (const float*)d_in[4];
    const float* b1    = (const float*)d_in[5];
    const float* w2    = (const float*)d_in[6];
    const float* b2    = (const float*)d_in[7];
    const float* gamma = (const float*)d_in[8];
    const float* beta  = (const float*)d_in[9];
    const float* wout  = (const float*)d_in[10];
    const float* bout  = (const float*)d_in[11];
    float* out = (float*)d_out;

    const int N = in_sizes[2];               // 100000
    const int E = in_sizes[1] / 2;           // 3200000
    const int NB = (N + 127) >> 7;           // 782 buckets
    const int nblk = (E + CHUNK - 1) / CHUNK;// 391 scatter blocks

    // Workspace (~58 MB)
    unsigned short* hbX = (unsigned short*)d_ws;             // N*64 bf16
    unsigned short* hbY = hbX + (size_t)N * 64;              // N*64 bf16
    int* bucketed2 = (int*)(hbY + (size_t)N * 64);           // nblk*CHUNK
    int* offsTab   = bucketed2 + (size_t)nblk * CHUNK;       // nblk*1025
    int* csrOut    = offsTab + (size_t)nblk * 1025;          // NB*CAP
    int* rowstart  = csrOut + (size_t)NB * CAP;              // N
    int* rowend    = rowstart + N;                           // N
    float* bnstats = (float*)(rowend + N);                   // 6*64
    float* partS   = bnstats + 384;                          // NB*64
    float* partQ   = partS + (size_t)NB * 64;                // NB*64
    unsigned short* w1T0 = (unsigned short*)(partQ + (size_t)NB * 64); // 64*32
    unsigned short* w1T  = w1T0 + 64 * 32;                   // 2*64*64
    unsigned short* w2T  = w1T + 2 * 64 * 64;                // 3*64*64

    const int* srcv = ei;
    const int* dstv = ei + E;

    prep_weights<<<48, 256, 0, stream>>>(w1_0, w1_r, w2, w1T0, w1T, w2T);

    // --- CSR build ---
    scatter_sort<<<nblk, 512, 0, stream>>>(srcv, dstv, bucketed2, offsTab, E);
    bucket_csr<<<NB, 256, 0, stream>>>(bucketed2, offsTab, csrOut, rowstart, rowend, N, nblk);

    // --- Layer 0 (fused agg3 + MLP) ---
    gin_layer<true><<<NB, 256, 0, stream>>>(x, rowstart, rowend, csrOut,
                                            nullptr, nullptr, nullptr, nullptr,
                                            (const uint4*)w1T0, b1,
                                            (const uint4*)w2T, b2,
                                            (uint4*)hbX, partS, partQ, N);
    bn_reduce<<<64, 256, 0, stream>>>(partS, partQ, bnstats, bnstats + 64, NB);

    // --- Layer 1 (fused BN0+agg + MLP) ---
    gin_layer<false><<<NB, 256, 0, stream>>>(hbX, rowstart, rowend, csrOut,
                                             bnstats, bnstats + 64, gamma, beta,
                                             (const uint4*)w1T, b1 + 64,
                                             (const uint4*)(w2T + 4096), b2 + 64,
                                             (uint4*)hbY, partS, partQ, N);
    bn_reduce<<<64, 256, 0, stream>>>(partS, partQ, bnstats + 128, bnstats + 192, NB);

    // --- Layer 2 (fused BN1+agg + MLP) ---
    gin_layer<false><<<NB, 256, 0, stream>>>(hbY, rowstart, rowend, csrOut,
                                             bnstats + 128, bnstats + 192,
                                             gamma + 64, beta + 64,
                                             (const uint4*)(w1T + 4096), b1 + 128,
                                             (const uint4*)(w2T + 8192), b2 + 128,
                                             (uint4*)hbX, partS, partQ, N);
    bn_reduce<<<64, 256, 0, stream>>>(partS, partQ, bnstats + 256, bnstats + 320, NB);

    // --- BN2 apply + pool + output matmul ---
    bn_pool_out<<<512, 256, 0, stream>>>(hbX, batch, bnstats + 256, bnstats + 320,
                                         gamma + 128, beta + 128, wout, bout, out, N);
}

// Round 16
// 425.291 us; speedup vs baseline: 1.0175x; 1.0175x over previous
//
#include <hip/hip_runtime.h>

// GIN encoder: N=100k, E=3.2M, G=512, H=64, L=3.
// Round 16: fusion v2. gin_layer: one 64-node tile per block (grid 1563).
// Gather phase writes DIRECTLY into MFMA A-fragment registers: lane (m16,q)
// owns node m16's feature groups q and q+4 (2 uint4/edge, 16 fp32 accs) ->
// no acts LDS tile (R15's 32KB + 4-node serial gather caused 107us at 18%
// occupancy). LDS = mids 9KB + red 4KB only. Weights loaded AFTER gather
// (register pressure). Per-lane gather work identical to verified agg64_bn.
// bn_reduce v2, scatter_sort, bucket_csr v3, bn_pool_out from R14 (377us).

#define NBMAX 1024
#define CAP 4608
#define CHUNK 8192
#define NBLK_MAX 512
#define MSTR 72   // mids stride in shorts (9 uint4, bank-staggered)

typedef __attribute__((ext_vector_type(8))) short bf16x8;
typedef __attribute__((ext_vector_type(4))) float f32x4;

static __device__ __forceinline__ bf16x8 as_bf16x8(uint4 u) {
    union { uint4 a; bf16x8 b; } x; x.a = u; return x.b;
}
static __device__ __forceinline__ unsigned short bf16r(float v) {
    unsigned u = __float_as_uint(v);
    return (unsigned short)((u + 0x7FFFu + ((u >> 16) & 1u)) >> 16);
}
static __device__ __forceinline__ unsigned bf16pack2(float a, float b) {
    return (unsigned)bf16r(a) | ((unsigned)bf16r(b) << 16);
}

// ---- weight prep: bf16, transposed to [col][k] ----
__global__ void prep_weights(const float* __restrict__ w1_0, const float* __restrict__ w1_r,
                             const float* __restrict__ w2, unsigned short* __restrict__ w1T0,
                             unsigned short* __restrict__ w1T, unsigned short* __restrict__ w2T) {
    int t = blockIdx.x * 256 + threadIdx.x;
    if (t < 64 * 32) {
        int c = t >> 5, k = t & 31;
        w1T0[t] = bf16r(k < 3 ? w1_0[k * 64 + c] : 0.f);
    }
    if (t < 2 * 64 * 64) {
        int l = t >> 12, r = t & 4095, c = r >> 6, k = r & 63;
        w1T[t] = bf16r(w1_r[l * 4096 + k * 64 + c]);
    }
    if (t < 3 * 64 * 64) {
        int l = t >> 12, r = t & 4095, c = r >> 6, k = r & 63;
        w2T[t] = bf16r(w2[l * 4096 + k * 64 + c]);
    }
}

// ---- scatter_sort: block counting-sorts its 8192-edge chunk by bucket ----
__global__ __launch_bounds__(512) void scatter_sort(
    const int* __restrict__ src, const int* __restrict__ dst,
    int* __restrict__ bucketed2, int* __restrict__ offsTab, int E) {
    __shared__ int hist[NBMAX];
    __shared__ int offs[NBMAX];
    __shared__ int stage[CHUNK];
    int t = threadIdx.x, blk = blockIdx.x;
    int e0 = blk * CHUNK, e1 = min(e0 + CHUNK, E);
    int len = e1 - e0;
    hist[t] = 0; hist[t + 512] = 0;
    __syncthreads();
    for (int e = e0 + t; e < e1; e += 512) atomicAdd(&hist[dst[e] >> 7], 1);
    __syncthreads();
    offs[t] = hist[t]; offs[t + 512] = hist[t + 512];
    __syncthreads();
    for (int off = 1; off < 1024; off <<= 1) {
        int v0 = (t >= off) ? offs[t - off] : 0;
        int v1 = offs[t + 512 - off];
        __syncthreads();
        offs[t] += v0;
        offs[t + 512] += v1;
        __syncthreads();
    }
    offs[t] -= hist[t]; offs[t + 512] -= hist[t + 512];
    hist[t] = 0; hist[t + 512] = 0;
    __syncthreads();
    offsTab[blk * 1025 + t] = offs[t];
    offsTab[blk * 1025 + t + 512] = offs[t + 512];
    if (t == 0) offsTab[blk * 1025 + 1024] = len;
    for (int e = e0 + t; e < e1; e += 512) {
        int d = dst[e];
        int bk = d >> 7;
        int r = offs[bk] + atomicAdd(&hist[bk], 1);
        stage[r] = src[e] | ((d & 127) << 20);
    }
    __syncthreads();
    for (int j = t; j < len; j += 512) bucketed2[e0 + j] = stage[j];
}

// ---- bucket_csr v3: binsearch run-gather, counting sort by src-block, then
// by row -> CSR with ~src-ascending rows (L2 locality for agg) ----
__global__ __launch_bounds__(256) void bucket_csr(
    const int* __restrict__ bucketed2, const int* __restrict__ offsTab,
    int* __restrict__ csrOut, int* __restrict__ rowstart, int* __restrict__ rowend,
    int N, int nblk) {
    __shared__ int ein[CAP];
    __shared__ int emid[CAP];
    __shared__ int runs[NBLK_MAX];
    __shared__ int rbeg[NBLK_MAX];
    __shared__ int hist[128];
    __shared__ int base[129];
    int b = blockIdx.x, t = threadIdx.x, node0 = b << 7;
    for (int r = t; r < NBLK_MAX; r += 256) {
        int l = 0, g0 = 0;
        if (r < nblk) {
            int beg = offsTab[r * 1025 + b];
            int end = offsTab[r * 1025 + b + 1];
            l = end - beg;
            g0 = r * CHUNK + beg;
        }
        runs[r] = l;
        rbeg[r] = g0;
    }
    __syncthreads();
    for (int off = 1; off < NBLK_MAX; off <<= 1) {
        int v0 = (t >= off) ? runs[t - off] : 0;
        int v1 = (t + 256 >= off) ? runs[t + 256 - off] : 0;
        __syncthreads();
        runs[t] += v0;
        runs[t + 256] += v1;
        __syncthreads();
    }
    int cnt = min(runs[NBLK_MAX - 1], CAP);
    for (int j = t; j < cnt; j += 256) {
        int lo = 0, hi = nblk - 1;
        while (lo < hi) {
            int m = (lo + hi) >> 1;
            if (runs[m] > j) hi = m; else lo = m + 1;
        }
        int st = lo ? runs[lo - 1] : 0;
        ein[j] = bucketed2[rbeg[lo] + (j - st)];
    }
    // pass 1: group by src block (src>>10)
    if (t < 128) hist[t] = 0;
    __syncthreads();
    for (int j = t; j < cnt; j += 256) atomicAdd(&hist[(ein[j] & 0xFFFFF) >> 10], 1);
    __syncthreads();
    if (t < 128) base[t + 1] = hist[t];
    if (t == 0) base[0] = 0;
    __syncthreads();
    for (int off = 1; off < 128; off <<= 1) {
        int v = 0;
        if (t < 128 && (t + 1) > off) v = base[t + 1 - off];
        __syncthreads();
        if (t < 128 && (t + 1) > off) base[t + 1] += v;
        __syncthreads();
    }
    if (t < 128) hist[t] = 0;
    __syncthreads();
    for (int j = t; j < cnt; j += 256) {
        int p = ein[j];
        int sb = (p & 0xFFFFF) >> 10;
        int pos = base[sb] + atomicAdd(&hist[sb], 1);
        emid[pos] = p;
    }
    __syncthreads();
    // pass 2: counting sort by row
    if (t < 128) hist[t] = 0;
    __syncthreads();
    for (int j = t; j < cnt; j += 256) atomicAdd(&hist[emid[j] >> 20], 1);
    __syncthreads();
    if (t < 128) base[t + 1] = hist[t];
    if (t == 0) base[0] = 0;
    __syncthreads();
    for (int off = 1; off < 128; off <<= 1) {
        int v = 0;
        if (t < 128 && (t + 1) > off) v = base[t + 1 - off];
        __syncthreads();
        if (t < 128 && (t + 1) > off) base[t + 1] += v;
        __syncthreads();
    }
    if (t < 128) {
        int n = node0 + t;
        if (n < N) {
            rowstart[n] = b * CAP + base[t];
            rowend[n] = b * CAP + base[t + 1];
        }
        hist[t] = 0;
    }
    __syncthreads();
    for (int j = t; j < cnt; j += 256) {
        int p = emid[j];
        int local = p >> 20;
        int pos = base[local] + atomicAdd(&hist[local], 1);
        ein[pos] = p & 0xFFFFF;
    }
    __syncthreads();
    for (int j = t; j < cnt; j += 256) csrOut[b * CAP + j] = ein[j];
}

// bf16x2-packed accumulate of relu(v*sc+sh)
__device__ __forceinline__ void accum_bf16(const uint4 u,
                                           const float4 scA, const float4 scB,
                                           const float4 shA, const float4 shB,
                                           float* __restrict__ a) {
    a[0] += fmaxf(__uint_as_float(u.x << 16) * scA.x + shA.x, 0.f);
    a[1] += fmaxf(__uint_as_float(u.x & 0xFFFF0000u) * scA.y + shA.y, 0.f);
    a[2] += fmaxf(__uint_as_float(u.y << 16) * scA.z + shA.z, 0.f);
    a[3] += fmaxf(__uint_as_float(u.y & 0xFFFF0000u) * scA.w + shA.w, 0.f);
    a[4] += fmaxf(__uint_as_float(u.z << 16) * scB.x + shB.x, 0.f);
    a[5] += fmaxf(__uint_as_float(u.z & 0xFFFF0000u) * scB.y + shB.y, 0.f);
    a[6] += fmaxf(__uint_as_float(u.w << 16) * scB.z + shB.z, 0.f);
    a[7] += fmaxf(__uint_as_float(u.w & 0xFFFF0000u) * scB.w + shB.w, 0.f);
}

// ---- fused GIN layer v2: 64-node tile/block; gather -> A-frag registers;
// MFMA MLP; coalesced epilogue; BN partials to private slots ----
template <bool L0>
__global__ __launch_bounds__(256) void gin_layer(
    const void* __restrict__ actInRaw,      // L0: float* x (d=3); else uint4* h
    const int* __restrict__ rowstart, const int* __restrict__ rowend,
    const int* __restrict__ csr,
    const float* __restrict__ bnsumPrev, const float* __restrict__ bnsqPrev,
    const float* __restrict__ gammaPrev, const float* __restrict__ betaPrev,
    const uint4* __restrict__ w1Tu, const float* __restrict__ b1,
    const uint4* __restrict__ w2Tu, const float* __restrict__ b2,
    uint4* __restrict__ houtU4,
    float* __restrict__ partS, float* __restrict__ partQ, int N) {
    __shared__ __align__(16) unsigned short mids[64 * MSTR];  // 9KB
    __shared__ float red[16][64];                             // 4KB
    __shared__ float scs[64], shs[64];
    int t = threadIdx.x;
    int w = t >> 6, l64 = t & 63, m16 = l64 & 15, q = l64 >> 4;
    int tileBase = blockIdx.x * 64;
    int n = tileBase + w * 16 + m16;
    const uint4 z4 = make_uint4(0, 0, 0, 0);

    if (!L0) {
        if (t < 64) {
            float mu = bnsumPrev[t] / (float)N;
            float var = bnsqPrev[t] / (float)N - mu * mu;
            float s = gammaPrev[t] * rsqrtf(var + 1e-5f);
            scs[t] = s;
            shs[t] = betaPrev[t] - mu * s;
        }
        __syncthreads();
    }

    // ---- gather phase: accumulate directly into A-fragment layout ----
    bf16x8 a0, a1;
    if (L0) {
        const float* x = (const float*)actInRaw;
        float s0 = 0.f, s1 = 0.f, s2 = 0.f;
        if (q == 0 && n < N) {
            s0 = x[n * 3]; s1 = x[n * 3 + 1]; s2 = x[n * 3 + 2];
            float b0 = 0.f, b1v = 0.f, b2v = 0.f;
            float c0 = 0.f, c1 = 0.f, c2 = 0.f;
            float d0 = 0.f, d1 = 0.f, d2 = 0.f;
            int s = rowstart[n], e = rowend[n];
            int j = s;
            for (; j + 3 < e; j += 4) {
                int i0 = csr[j], i1 = csr[j + 1], i2 = csr[j + 2], i3 = csr[j + 3];
                s0 += x[i0 * 3]; s1 += x[i0 * 3 + 1]; s2 += x[i0 * 3 + 2];
                b0 += x[i1 * 3]; b1v += x[i1 * 3 + 1]; b2v += x[i1 * 3 + 2];
                c0 += x[i2 * 3]; c1 += x[i2 * 3 + 1]; c2 += x[i2 * 3 + 2];
                d0 += x[i3 * 3]; d1 += x[i3 * 3 + 1]; d2 += x[i3 * 3 + 2];
            }
            for (; j < e; j++) {
                int nb = csr[j];
                s0 += x[nb * 3]; s1 += x[nb * 3 + 1]; s2 += x[nb * 3 + 2];
            }
            s0 += b0 + c0 + d0; s1 += b1v + c1 + d1; s2 += b2v + c2 + d2;
        }
        uint4 av = make_uint4(bf16pack2(s0, s1), bf16pack2(s2, 0.f), 0u, 0u);
        a0 = as_bf16x8(q == 0 ? av : z4);
        a1 = as_bf16x8(z4);
    } else {
        const uint4* hr = (const uint4*)actInRaw;
        int cL = q * 8, cH = 32 + q * 8;
        float4 scLa = *(const float4*)&scs[cL], scLb = *(const float4*)&scs[cL + 4];
        float4 shLa = *(const float4*)&shs[cL], shLb = *(const float4*)&shs[cL + 4];
        float4 scHa = *(const float4*)&scs[cH], scHb = *(const float4*)&scs[cH + 4];
        float4 shHa = *(const float4*)&shs[cH], shHb = *(const float4*)&shs[cH + 4];
        float AL[8] = {0,0,0,0,0,0,0,0}, AH[8] = {0,0,0,0,0,0,0,0};
        float BL[8] = {0,0,0,0,0,0,0,0}, BH[8] = {0,0,0,0,0,0,0,0};
        if (n < N) {
            accum_bf16(hr[(size_t)n * 8 + q], scLa, scLb, shLa, shLb, AL);      // self
            accum_bf16(hr[(size_t)n * 8 + 4 + q], scHa, scHb, shHa, shHb, AH);
            int s = rowstart[n], e = rowend[n];
            int j = s;
            for (; j + 1 < e; j += 2) {
                int i0 = csr[j], i1 = csr[j + 1];
                uint4 u0l = hr[(size_t)i0 * 8 + q];
                uint4 u0h = hr[(size_t)i0 * 8 + 4 + q];
                uint4 u1l = hr[(size_t)i1 * 8 + q];
                uint4 u1h = hr[(size_t)i1 * 8 + 4 + q];
                accum_bf16(u0l, scLa, scLb, shLa, shLb, AL);
                accum_bf16(u0h, scHa, scHb, shHa, shHb, AH);
                accum_bf16(u1l, scLa, scLb, shLa, shLb, BL);
                accum_bf16(u1h, scHa, scHb, shHa, shHb, BH);
            }
            if (j < e) {
                int i0 = csr[j];
                accum_bf16(hr[(size_t)i0 * 8 + q], scLa, scLb, shLa, shLb, AL);
                accum_bf16(hr[(size_t)i0 * 8 + 4 + q], scHa, scHb, shHa, shHb, AH);
            }
        }
        uint4 ua, ub;
        ua.x = bf16pack2(AL[0] + BL[0], AL[1] + BL[1]);
        ua.y = bf16pack2(AL[2] + BL[2], AL[3] + BL[3]);
        ua.z = bf16pack2(AL[4] + BL[4], AL[5] + BL[5]);
        ua.w = bf16pack2(AL[6] + BL[6], AL[7] + BL[7]);
        ub.x = bf16pack2(AH[0] + BH[0], AH[1] + BH[1]);
        ub.y = bf16pack2(AH[2] + BH[2], AH[3] + BH[3]);
        ub.z = bf16pack2(AH[4] + BH[4], AH[5] + BH[5]);
        ub.w = bf16pack2(AH[6] + BH[6], AH[7] + BH[7]);
        a0 = as_bf16x8(ua);
        a1 = as_bf16x8(ub);
    }

    // ---- MLP phase (weights loaded after gather to cap reg pressure) ----
    bf16x8 w1f[4][2], w2f[4][2];
    float bias1[4], bias2[4];
#pragma unroll
    for (int c = 0; c < 4; c++) {
        int col = c * 16 + m16;
        if (L0) {
            w1f[c][0] = as_bf16x8(w1Tu[col * 4 + q]);
        } else {
            w1f[c][0] = as_bf16x8(w1Tu[col * 8 + q]);
            w1f[c][1] = as_bf16x8(w1Tu[col * 8 + 4 + q]);
        }
        w2f[c][0] = as_bf16x8(w2Tu[col * 8 + q]);
        w2f[c][1] = as_bf16x8(w2Tu[col * 8 + 4 + q]);
        bias1[c] = b1[col];
        bias2[c] = b2[col];
    }
#pragma unroll
    for (int c = 0; c < 4; c++) {
        float bias = bias1[c];
        f32x4 acc = {bias, bias, bias, bias};
        if (L0) {
            acc = __builtin_amdgcn_mfma_f32_16x16x32_bf16(a0, w1f[c][0], acc, 0, 0, 0);
        } else {
            acc = __builtin_amdgcn_mfma_f32_16x16x32_bf16(a0, w1f[c][0], acc, 0, 0, 0);
            acc = __builtin_amdgcn_mfma_f32_16x16x32_bf16(a1, w1f[c][1], acc, 0, 0, 0);
        }
        int col = c * 16 + m16;
#pragma unroll
        for (int r = 0; r < 4; r++) {
            int row = w * 16 + q * 4 + r;
            mids[row * MSTR + col] = bf16r(fmaxf(acc[r], 0.f));
        }
    }
    __syncthreads();
    int rowM = w * 16 + m16;
    const uint4* midU4 = (const uint4*)mids;
    bf16x8 a20 = as_bf16x8(midU4[rowM * 9 + q]);
    bf16x8 a21 = as_bf16x8(midU4[rowM * 9 + 4 + q]);
    f32x4 accs[4];
#pragma unroll
    for (int c = 0; c < 4; c++) {
        float bias = bias2[c];
        f32x4 acc = {bias, bias, bias, bias};
        acc = __builtin_amdgcn_mfma_f32_16x16x32_bf16(a20, w2f[c][0], acc, 0, 0, 0);
        acc = __builtin_amdgcn_mfma_f32_16x16x32_bf16(a21, w2f[c][1], acc, 0, 0, 0);
        accs[c] = acc;
    }
    __syncthreads();  // all mids reads done -> reuse as output staging
    float s[4] = {0, 0, 0, 0}, sq[4] = {0, 0, 0, 0};
#pragma unroll
    for (int c = 0; c < 4; c++) {
        int col = c * 16 + m16;
#pragma unroll
        for (int r = 0; r < 4; r++) {
            int row = w * 16 + q * 4 + r;
            float v = accs[c][r];
            if (tileBase + row < N) { s[c] += v; sq[c] += v * v; }
            mids[row * MSTR + col] = bf16r(v);
        }
    }
    __syncthreads();
    for (int i = t; i < 512; i += 256) {
        int row = i >> 3, qo = i & 7;
        int gr = tileBase + row;
        if (gr < N) houtU4[(size_t)gr * 8 + qo] = midU4[row * 9 + qo];
    }
    // BN partial reduce -> private global slot
    for (int c = 0; c < 4; c++) red[w * 4 + q][c * 16 + m16] = s[c];
    __syncthreads();
    if (t < 64) {
        float S = 0.f;
        for (int i = 0; i < 16; i++) S += red[i][t];
        partS[blockIdx.x * 64 + t] = S;
    }
    __syncthreads();
    for (int c = 0; c < 4; c++) red[w * 4 + q][c * 16 + m16] = sq[c];
    __syncthreads();
    if (t < 64) {
        float S = 0.f;
        for (int i = 0; i < 16; i++) S += red[i][t];
        partQ[blockIdx.x * 64 + t] = S;
    }
}

// ---- bn_reduce v2: 64 blocks, block b reduces column b over nParts ----
__global__ __launch_bounds__(256) void bn_reduce(
    const float* __restrict__ partS, const float* __restrict__ partQ,
    float* __restrict__ bnsum, float* __restrict__ bnsq, int nParts) {
    __shared__ float rs[256], rq[256];
    int b = blockIdx.x, t = threadIdx.x;
    float S = 0.f, Q = 0.f;
    for (int p = t; p < nParts; p += 256) {
        S += partS[p * 64 + b];
        Q += partQ[p * 64 + b];
    }
    rs[t] = S; rq[t] = Q;
    __syncthreads();
    for (int off = 128; off > 0; off >>= 1) {
        if (t < off) { rs[t] += rs[t + off]; rq[t] += rq[t + off]; }
        __syncthreads();
    }
    if (t == 0) { bnsum[b] = rs[0]; bnsq[b] = rq[0]; }
}

// ---- BN apply + mean-pool + output matmul (batch sorted; zero atomics) ----
__device__ __forceinline__ int lowb(const int* __restrict__ a, int n, int v) {
    int lo = 0, hi = n;
    while (lo < hi) {
        int m = (lo + hi) >> 1;
        if (a[m] < v) lo = m + 1; else hi = m;
    }
    return lo;
}

__global__ __launch_bounds__(256) void bn_pool_out(
    const unsigned short* __restrict__ h, const int* __restrict__ batch,
    const float* __restrict__ bnsum, const float* __restrict__ bnsq,
    const float* __restrict__ gamma, const float* __restrict__ beta,
    const float* __restrict__ wout, const float* __restrict__ bout,
    float* __restrict__ out, int N) {
    __shared__ float sc[64], sh[64];
    __shared__ float part[4][64];
    __shared__ float gr[64];
    __shared__ int range[2];
    int g = blockIdx.x, t = threadIdx.x;
    if (t < 64) {
        float mu = bnsum[t] / (float)N;
        float var = bnsq[t] / (float)N - mu * mu;
        float s = gamma[t] * rsqrtf(var + 1e-5f);
        sc[t] = s;
        sh[t] = beta[t] - mu * s;
    }
    if (t == 64) range[0] = lowb(batch, N, g);
    if (t == 65) range[1] = lowb(batch, N, g + 1);
    __syncthreads();
    int s0 = range[0], s1 = range[1];
    int col = t & 63, ro = t >> 6;
    float acc = 0.f;
    for (int n = s0 + ro; n < s1; n += 4) {
        float v = __uint_as_float(((unsigned)h[(size_t)n * 64 + col]) << 16);
        acc += fmaxf(v * sc[col] + sh[col], 0.f);
    }
    part[ro][col] = acc;
    __syncthreads();
    if (t < 64) {
        float S = part[0][t] + part[1][t] + part[2][t] + part[3][t];
        float c = (float)(s1 - s0);
        gr[t] = (c > 0.f) ? S / c : 0.f;
    }
    __syncthreads();
    if (t < 64) {
        float a = bout[t];
        for (int f = 0; f < 64; f++) a += gr[f] * wout[f * 64 + t];
        out[g * 64 + t] = a;
    }
}

extern "C" void kernel_launch(void* const* d_in, const int* in_sizes, int n_in,
                              void* d_out, int out_size, void* d_ws, size_t ws_size,
                              hipStream_t stream) {
    const float* x     = (const float*)d_in[0];
    const int*   ei    = (const int*)d_in[1];
    const int*   batch = (const int*)d_in[2];
    const float* w1_0  = (const float*)d_in[3];
    const float* w1_r  = (const float*)d_in[4];
    const float* b1    = (const float*)d_in[5];
    const float* w2    = (const float*)d_in[6];
    const float* b2    = (const float*)d_in[7];
    const float* gamma = (const float*)d_in[8];
    const float* beta  = (const float*)d_in[9];
    const float* wout  = (const float*)d_in[10];
    const float* bout  = (const float*)d_in[11];
    float* out = (float*)d_out;

    const int N = in_sizes[2];               // 100000
    const int E = in_sizes[1] / 2;           // 3200000
    const int NB = (N + 127) >> 7;           // 782 buckets
    const int nblk = (E + CHUNK - 1) / CHUNK;// 391 scatter blocks
    const int nTiles = (N + 63) >> 6;        // 1563 layer tiles

    // Workspace (~58 MB)
    unsigned short* hbX = (unsigned short*)d_ws;             // N*64 bf16
    unsigned short* hbY = hbX + (size_t)N * 64;              // N*64 bf16
    int* bucketed2 = (int*)(hbY + (size_t)N * 64);           // nblk*CHUNK
    int* offsTab   = bucketed2 + (size_t)nblk * CHUNK;       // nblk*1025
    int* csrOut    = offsTab + (size_t)nblk * 1025;          // NB*CAP
    int* rowstart  = csrOut + (size_t)NB * CAP;              // N
    int* rowend    = rowstart + N;                           // N
    float* bnstats = (float*)(rowend + N);                   // 6*64
    float* partS   = bnstats + 384;                          // nTiles*64
    float* partQ   = partS + (size_t)nTiles * 64;            // nTiles*64
    unsigned short* w1T0 = (unsigned short*)(partQ + (size_t)nTiles * 64); // 64*32
    unsigned short* w1T  = w1T0 + 64 * 32;                   // 2*64*64
    unsigned short* w2T  = w1T + 2 * 64 * 64;                // 3*64*64

    const int* srcv = ei;
    const int* dstv = ei + E;

    prep_weights<<<48, 256, 0, stream>>>(w1_0, w1_r, w2, w1T0, w1T, w2T);

    // --- CSR build ---
    scatter_sort<<<nblk, 512, 0, stream>>>(srcv, dstv, bucketed2, offsTab, E);
    bucket_csr<<<NB, 256, 0, stream>>>(bucketed2, offsTab, csrOut, rowstart, rowend, N, nblk);

    // --- Layer 0 (fused agg3 + MLP) ---
    gin_layer<true><<<nTiles, 256, 0, stream>>>(x, rowstart, rowend, csrOut,
                                                nullptr, nullptr, nullptr, nullptr,
                                                (const uint4*)w1T0, b1,
                                                (const uint4*)w2T, b2,
                                                (uint4*)hbX, partS, partQ, N);
    bn_reduce<<<64, 256, 0, stream>>>(partS, partQ, bnstats, bnstats + 64, nTiles);

    // --- Layer 1 (fused BN0+agg + MLP) ---
    gin_layer<false><<<nTiles, 256, 0, stream>>>(hbX, rowstart, rowend, csrOut,
                                                 bnstats, bnstats + 64, gamma, beta,
                                                 (const uint4*)w1T, b1 + 64,
                                                 (const uint4*)(w2T + 4096), b2 + 64,
                                                 (uint4*)hbY, partS, partQ, N);
    bn_reduce<<<64, 256, 0, stream>>>(partS, partQ, bnstats + 128, bnstats + 192, nTiles);

    // --- Layer 2 (fused BN1+agg + MLP) ---
    gin_layer<false><<<nTiles, 256, 0, stream>>>(hbY, rowstart, rowend, csrOut,
                                                 bnstats + 128, bnstats + 192,
                                                 gamma + 64, beta + 64,
                                                 (const uint4*)(w1T + 4096), b1 + 128,
                                                 (const uint4*)(w2T + 8192), b2 + 128,
                                                 (uint4*)hbX, partS, partQ, N);
    bn_reduce<<<64, 256, 0, stream>>>(partS, partQ, bnstats + 256, bnstats + 320, nTiles);

    // --- BN2 apply + pool + output matmul ---
    bn_pool_out<<<512, 256, 0, stream>>>(hbX, batch, bnstats + 256, bnstats + 320,
                                         gamma + 128, beta + 128, wout, bout, out, N);
}

// Round 17
// 378.112 us; speedup vs baseline: 1.1445x; 1.1248x over previous
//
#include <hip/hip_runtime.h>

// GIN encoder: N=100k, E=3.2M, G=512, H=64, L=3.
// Round 17: fusion v3. 512-thread blocks, 64-node tile. Gather phase keeps
// the verified agg64_bn geometry (8 lanes/node, 1 uint4/edge, 512 slices =
// 1/thread -> same 800k-thread parallelism as the standalone 54us agg) into
// a 9KB LDS acts tile. MFMA phase: 8 waves split the 64x64 output (wave w:
// rows (w&3)*16, col half (w>>2)*32, 2 col-groups -> 32 weight VGPRs).
// R16's 4-lane/node direct-to-A-frag gather (halved MLP, doubled chain ->
// 101us) abandoned. bn_reduce v2, scatter_sort, bucket_csr v3, bn_pool_out
// unchanged from R14 (377us).

#define NBMAX 1024
#define CAP 4608
#define CHUNK 8192
#define NBLK_MAX 512
#define MSTR 72   // LDS row stride in shorts (9 uint4, bank-staggered)

typedef __attribute__((ext_vector_type(8))) short bf16x8;
typedef __attribute__((ext_vector_type(4))) float f32x4;

static __device__ __forceinline__ bf16x8 as_bf16x8(uint4 u) {
    union { uint4 a; bf16x8 b; } x; x.a = u; return x.b;
}
static __device__ __forceinline__ unsigned short bf16r(float v) {
    unsigned u = __float_as_uint(v);
    return (unsigned short)((u + 0x7FFFu + ((u >> 16) & 1u)) >> 16);
}
static __device__ __forceinline__ unsigned bf16pack2(float a, float b) {
    return (unsigned)bf16r(a) | ((unsigned)bf16r(b) << 16);
}

// ---- weight prep: bf16, transposed to [col][k] ----
__global__ void prep_weights(const float* __restrict__ w1_0, const float* __restrict__ w1_r,
                             const float* __restrict__ w2, unsigned short* __restrict__ w1T0,
                             unsigned short* __restrict__ w1T, unsigned short* __restrict__ w2T) {
    int t = blockIdx.x * 256 + threadIdx.x;
    if (t < 64 * 32) {
        int c = t >> 5, k = t & 31;
        w1T0[t] = bf16r(k < 3 ? w1_0[k * 64 + c] : 0.f);
    }
    if (t < 2 * 64 * 64) {
        int l = t >> 12, r = t & 4095, c = r >> 6, k = r & 63;
        w1T[t] = bf16r(w1_r[l * 4096 + k * 64 + c]);
    }
    if (t < 3 * 64 * 64) {
        int l = t >> 12, r = t & 4095, c = r >> 6, k = r & 63;
        w2T[t] = bf16r(w2[l * 4096 + k * 64 + c]);
    }
}

// ---- scatter_sort: block counting-sorts its 8192-edge chunk by bucket ----
__global__ __launch_bounds__(512) void scatter_sort(
    const int* __restrict__ src, const int* __restrict__ dst,
    int* __restrict__ bucketed2, int* __restrict__ offsTab, int E) {
    __shared__ int hist[NBMAX];
    __shared__ int offs[NBMAX];
    __shared__ int stage[CHUNK];
    int t = threadIdx.x, blk = blockIdx.x;
    int e0 = blk * CHUNK, e1 = min(e0 + CHUNK, E);
    int len = e1 - e0;
    hist[t] = 0; hist[t + 512] = 0;
    __syncthreads();
    for (int e = e0 + t; e < e1; e += 512) atomicAdd(&hist[dst[e] >> 7], 1);
    __syncthreads();
    offs[t] = hist[t]; offs[t + 512] = hist[t + 512];
    __syncthreads();
    for (int off = 1; off < 1024; off <<= 1) {
        int v0 = (t >= off) ? offs[t - off] : 0;
        int v1 = offs[t + 512 - off];
        __syncthreads();
        offs[t] += v0;
        offs[t + 512] += v1;
        __syncthreads();
    }
    offs[t] -= hist[t]; offs[t + 512] -= hist[t + 512];
    hist[t] = 0; hist[t + 512] = 0;
    __syncthreads();
    offsTab[blk * 1025 + t] = offs[t];
    offsTab[blk * 1025 + t + 512] = offs[t + 512];
    if (t == 0) offsTab[blk * 1025 + 1024] = len;
    for (int e = e0 + t; e < e1; e += 512) {
        int d = dst[e];
        int bk = d >> 7;
        int r = offs[bk] + atomicAdd(&hist[bk], 1);
        stage[r] = src[e] | ((d & 127) << 20);
    }
    __syncthreads();
    for (int j = t; j < len; j += 512) bucketed2[e0 + j] = stage[j];
}

// ---- bucket_csr v3: binsearch run-gather, counting sort by src-block, then
// by row -> CSR with ~src-ascending rows (L2 locality for agg) ----
__global__ __launch_bounds__(256) void bucket_csr(
    const int* __restrict__ bucketed2, const int* __restrict__ offsTab,
    int* __restrict__ csrOut, int* __restrict__ rowstart, int* __restrict__ rowend,
    int N, int nblk) {
    __shared__ int ein[CAP];
    __shared__ int emid[CAP];
    __shared__ int runs[NBLK_MAX];
    __shared__ int rbeg[NBLK_MAX];
    __shared__ int hist[128];
    __shared__ int base[129];
    int b = blockIdx.x, t = threadIdx.x, node0 = b << 7;
    for (int r = t; r < NBLK_MAX; r += 256) {
        int l = 0, g0 = 0;
        if (r < nblk) {
            int beg = offsTab[r * 1025 + b];
            int end = offsTab[r * 1025 + b + 1];
            l = end - beg;
            g0 = r * CHUNK + beg;
        }
        runs[r] = l;
        rbeg[r] = g0;
    }
    __syncthreads();
    for (int off = 1; off < NBLK_MAX; off <<= 1) {
        int v0 = (t >= off) ? runs[t - off] : 0;
        int v1 = (t + 256 >= off) ? runs[t + 256 - off] : 0;
        __syncthreads();
        runs[t] += v0;
        runs[t + 256] += v1;
        __syncthreads();
    }
    int cnt = min(runs[NBLK_MAX - 1], CAP);
    for (int j = t; j < cnt; j += 256) {
        int lo = 0, hi = nblk - 1;
        while (lo < hi) {
            int m = (lo + hi) >> 1;
            if (runs[m] > j) hi = m; else lo = m + 1;
        }
        int st = lo ? runs[lo - 1] : 0;
        ein[j] = bucketed2[rbeg[lo] + (j - st)];
    }
    // pass 1: group by src block (src>>10)
    if (t < 128) hist[t] = 0;
    __syncthreads();
    for (int j = t; j < cnt; j += 256) atomicAdd(&hist[(ein[j] & 0xFFFFF) >> 10], 1);
    __syncthreads();
    if (t < 128) base[t + 1] = hist[t];
    if (t == 0) base[0] = 0;
    __syncthreads();
    for (int off = 1; off < 128; off <<= 1) {
        int v = 0;
        if (t < 128 && (t + 1) > off) v = base[t + 1 - off];
        __syncthreads();
        if (t < 128 && (t + 1) > off) base[t + 1] += v;
        __syncthreads();
    }
    if (t < 128) hist[t] = 0;
    __syncthreads();
    for (int j = t; j < cnt; j += 256) {
        int p = ein[j];
        int sb = (p & 0xFFFFF) >> 10;
        int pos = base[sb] + atomicAdd(&hist[sb], 1);
        emid[pos] = p;
    }
    __syncthreads();
    // pass 2: counting sort by row
    if (t < 128) hist[t] = 0;
    __syncthreads();
    for (int j = t; j < cnt; j += 256) atomicAdd(&hist[emid[j] >> 20], 1);
    __syncthreads();
    if (t < 128) base[t + 1] = hist[t];
    if (t == 0) base[0] = 0;
    __syncthreads();
    for (int off = 1; off < 128; off <<= 1) {
        int v = 0;
        if (t < 128 && (t + 1) > off) v = base[t + 1 - off];
        __syncthreads();
        if (t < 128 && (t + 1) > off) base[t + 1] += v;
        __syncthreads();
    }
    if (t < 128) {
        int n = node0 + t;
        if (n < N) {
            rowstart[n] = b * CAP + base[t];
            rowend[n] = b * CAP + base[t + 1];
        }
        hist[t] = 0;
    }
    __syncthreads();
    for (int j = t; j < cnt; j += 256) {
        int p = emid[j];
        int local = p >> 20;
        int pos = base[local] + atomicAdd(&hist[local], 1);
        ein[pos] = p & 0xFFFFF;
    }
    __syncthreads();
    for (int j = t; j < cnt; j += 256) csrOut[b * CAP + j] = ein[j];
}

// bf16x2-packed accumulate of relu(v*sc+sh)
__device__ __forceinline__ void accum_bf16(const uint4 u,
                                           const float4 scA, const float4 scB,
                                           const float4 shA, const float4 shB,
                                           float* __restrict__ a) {
    a[0] += fmaxf(__uint_as_float(u.x << 16) * scA.x + shA.x, 0.f);
    a[1] += fmaxf(__uint_as_float(u.x & 0xFFFF0000u) * scA.y + shA.y, 0.f);
    a[2] += fmaxf(__uint_as_float(u.y << 16) * scA.z + shA.z, 0.f);
    a[3] += fmaxf(__uint_as_float(u.y & 0xFFFF0000u) * scA.w + shA.w, 0.f);
    a[4] += fmaxf(__uint_as_float(u.z << 16) * scB.x + shB.x, 0.f);
    a[5] += fmaxf(__uint_as_float(u.z & 0xFFFF0000u) * scB.y + shB.y, 0.f);
    a[6] += fmaxf(__uint_as_float(u.w << 16) * scB.z + shB.z, 0.f);
    a[7] += fmaxf(__uint_as_float(u.w & 0xFFFF0000u) * scB.w + shB.w, 0.f);
}

// ---- fused GIN layer v3: 512 threads, 64-node tile.
// gather: 8 lanes/node (1 slice/thread, agg64_bn geometry) -> LDS acts;
// MFMA: 8 waves, wave w = rows (w&3)*16, col-half (w>>2)*32. ----
template <bool L0>
__global__ __launch_bounds__(512) void gin_layer(
    const void* __restrict__ actInRaw,      // L0: float* x (d=3); else uint4* h
    const int* __restrict__ rowstart, const int* __restrict__ rowend,
    const int* __restrict__ csr,
    const float* __restrict__ bnsumPrev, const float* __restrict__ bnsqPrev,
    const float* __restrict__ gammaPrev, const float* __restrict__ betaPrev,
    const uint4* __restrict__ w1Tu, const float* __restrict__ b1,
    const uint4* __restrict__ w2Tu, const float* __restrict__ b2,
    uint4* __restrict__ houtU4,
    float* __restrict__ partS, float* __restrict__ partQ, int N) {
    __shared__ __align__(16) unsigned short acts[64 * MSTR];  // 9KB
    __shared__ __align__(16) unsigned short mids[64 * MSTR];  // 9KB
    __shared__ float red[16][64];                             // 4KB
    __shared__ float scs[64], shs[64];
    int t = threadIdx.x;
    int tileBase = blockIdx.x * 64;
    uint4* actsU4 = (uint4*)acts;
    const uint4* midU4 = (const uint4*)mids;
    const uint4 z4 = make_uint4(0, 0, 0, 0);

    if (!L0) {
        if (t < 64) {
            float mu = bnsumPrev[t] / (float)N;
            float var = bnsqPrev[t] / (float)N - mu * mu;
            float s = gammaPrev[t] * rsqrtf(var + 1e-5f);
            scs[t] = s;
            shs[t] = betaPrev[t] - mu * s;
        }
        __syncthreads();
    }

    // ---- gather phase: node = t>>3, slice l = t&7 (8 lanes/node) ----
    {
        int ni = t >> 3, l = t & 7;
        int n = tileBase + ni;
        if (L0) {
            const float* x = (const float*)actInRaw;
            uint4 o = z4;
            if (l == 0 && n < N) {
                float s0 = x[n * 3], s1 = x[n * 3 + 1], s2 = x[n * 3 + 2];
                float b0 = 0.f, b1v = 0.f, b2v = 0.f;
                float c0 = 0.f, c1 = 0.f, c2 = 0.f;
                float d0 = 0.f, d1 = 0.f, d2 = 0.f;
                int s = rowstart[n], e = rowend[n];
                int j = s;
                for (; j + 3 < e; j += 4) {
                    int i0 = csr[j], i1 = csr[j + 1], i2 = csr[j + 2], i3 = csr[j + 3];
                    s0 += x[i0 * 3]; s1 += x[i0 * 3 + 1]; s2 += x[i0 * 3 + 2];
                    b0 += x[i1 * 3]; b1v += x[i1 * 3 + 1]; b2v += x[i1 * 3 + 2];
                    c0 += x[i2 * 3]; c1 += x[i2 * 3 + 1]; c2 += x[i2 * 3 + 2];
                    d0 += x[i3 * 3]; d1 += x[i3 * 3 + 1]; d2 += x[i3 * 3 + 2];
                }
                for (; j < e; j++) {
                    int nb = csr[j];
                    s0 += x[nb * 3]; s1 += x[nb * 3 + 1]; s2 += x[nb * 3 + 2];
                }
                s0 += b0 + c0 + d0; s1 += b1v + c1 + d1; s2 += b2v + c2 + d2;
                o = make_uint4(bf16pack2(s0, s1), bf16pack2(s2, 0.f), 0u, 0u);
            }
            actsU4[ni * 9 + l] = o;
        } else {
            const uint4* hr = (const uint4*)actInRaw;
            int c0i = l * 8;
            float4 scA = *(const float4*)&scs[c0i], scB = *(const float4*)&scs[c0i + 4];
            float4 shA = *(const float4*)&shs[c0i], shB = *(const float4*)&shs[c0i + 4];
            float A[8] = {0,0,0,0,0,0,0,0};
            float B[8] = {0,0,0,0,0,0,0,0};
            if (n < N) {
                accum_bf16(hr[(size_t)n * 8 + l], scA, scB, shA, shB, A);  // self
                int s = rowstart[n], e = rowend[n];
                int j = s;
                for (; j + 3 < e; j += 4) {
                    int i0 = csr[j], i1 = csr[j + 1], i2 = csr[j + 2], i3 = csr[j + 3];
                    uint4 w0 = hr[(size_t)i0 * 8 + l];
                    uint4 w1 = hr[(size_t)i1 * 8 + l];
                    uint4 w2 = hr[(size_t)i2 * 8 + l];
                    uint4 w3 = hr[(size_t)i3 * 8 + l];
                    accum_bf16(w0, scA, scB, shA, shB, A);
                    accum_bf16(w1, scA, scB, shA, shB, B);
                    accum_bf16(w2, scA, scB, shA, shB, A);
                    accum_bf16(w3, scA, scB, shA, shB, B);
                }
                for (; j < e; j++) {
                    uint4 w = hr[(size_t)csr[j] * 8 + l];
                    accum_bf16(w, scA, scB, shA, shB, A);
                }
            }
            uint4 o;
            o.x = bf16pack2(A[0] + B[0], A[1] + B[1]);
            o.y = bf16pack2(A[2] + B[2], A[3] + B[3]);
            o.z = bf16pack2(A[4] + B[4], A[5] + B[5]);
            o.w = bf16pack2(A[6] + B[6], A[7] + B[7]);
            actsU4[ni * 9 + l] = o;
        }
    }

    // ---- MFMA phase: wave w -> rows (w&3)*16, col-half (w>>2)*32 ----
    int w = t >> 6, l64 = t & 63, m16 = l64 & 15, q = l64 >> 4;
    int wrow = (w & 3) * 16, cg0 = (w >> 2) * 32;
    bf16x8 w1f[2][2], w2f[2][2];
    float bias1[2], bias2[2];
#pragma unroll
    for (int c = 0; c < 2; c++) {
        int col = cg0 + c * 16 + m16;
        if (L0) {
            w1f[c][0] = as_bf16x8(w1Tu[col * 4 + q]);
        } else {
            w1f[c][0] = as_bf16x8(w1Tu[col * 8 + q]);
            w1f[c][1] = as_bf16x8(w1Tu[col * 8 + 4 + q]);
        }
        w2f[c][0] = as_bf16x8(w2Tu[col * 8 + q]);
        w2f[c][1] = as_bf16x8(w2Tu[col * 8 + 4 + q]);
        bias1[c] = b1[col];
        bias2[c] = b2[col];
    }
    __syncthreads();  // acts ready
    int rloc = wrow + m16;
    bf16x8 a0 = as_bf16x8(actsU4[rloc * 9 + q]);
    bf16x8 a1;
    if (!L0) a1 = as_bf16x8(actsU4[rloc * 9 + 4 + q]);
#pragma unroll
    for (int c = 0; c < 2; c++) {
        float bias = bias1[c];
        f32x4 acc = {bias, bias, bias, bias};
        if (L0) {
            acc = __builtin_amdgcn_mfma_f32_16x16x32_bf16(a0, w1f[c][0], acc, 0, 0, 0);
        } else {
            acc = __builtin_amdgcn_mfma_f32_16x16x32_bf16(a0, w1f[c][0], acc, 0, 0, 0);
            acc = __builtin_amdgcn_mfma_f32_16x16x32_bf16(a1, w1f[c][1], acc, 0, 0, 0);
        }
        int col = cg0 + c * 16 + m16;
#pragma unroll
        for (int r = 0; r < 4; r++) {
            int row = wrow + q * 4 + r;
            mids[row * MSTR + col] = bf16r(fmaxf(acc[r], 0.f));
        }
    }
    __syncthreads();
    bf16x8 a20 = as_bf16x8(midU4[rloc * 9 + q]);
    bf16x8 a21 = as_bf16x8(midU4[rloc * 9 + 4 + q]);
    f32x4 accs[2];
#pragma unroll
    for (int c = 0; c < 2; c++) {
        float bias = bias2[c];
        f32x4 acc = {bias, bias, bias, bias};
        acc = __builtin_amdgcn_mfma_f32_16x16x32_bf16(a20, w2f[c][0], acc, 0, 0, 0);
        acc = __builtin_amdgcn_mfma_f32_16x16x32_bf16(a21, w2f[c][1], acc, 0, 0, 0);
        accs[c] = acc;
    }
    __syncthreads();  // all mids reads done -> reuse as output staging
    float s2[2] = {0, 0}, sq2[2] = {0, 0};
#pragma unroll
    for (int c = 0; c < 2; c++) {
        int col = cg0 + c * 16 + m16;
#pragma unroll
        for (int r = 0; r < 4; r++) {
            int row = wrow + q * 4 + r;
            float v = accs[c][r];
            if (tileBase + row < N) { s2[c] += v; sq2[c] += v * v; }
            mids[row * MSTR + col] = bf16r(v);
        }
    }
    __syncthreads();
    // coalesced store: 64 rows x 8 uint4 = 512 u4, one per thread
    {
        int row = t >> 3, qo = t & 7;
        int gr = tileBase + row;
        if (gr < N) houtU4[(size_t)gr * 8 + qo] = midU4[row * 9 + qo];
    }
    // BN partial reduce: red rows (w&3)*4+q; waves w and w+4 fill disjoint cols
    for (int c = 0; c < 2; c++) red[(w & 3) * 4 + q][cg0 + c * 16 + m16] = s2[c];
    __syncthreads();
    if (t < 64) {
        float S = 0.f;
        for (int i = 0; i < 16; i++) S += red[i][t];
        partS[blockIdx.x * 64 + t] = S;
    }
    __syncthreads();
    for (int c = 0; c < 2; c++) red[(w & 3) * 4 + q][cg0 + c * 16 + m16] = sq2[c];
    __syncthreads();
    if (t < 64) {
        float S = 0.f;
        for (int i = 0; i < 16; i++) S += red[i][t];
        partQ[blockIdx.x * 64 + t] = S;
    }
}

// ---- bn_reduce v2: 64 blocks, block b reduces column b over nParts ----
__global__ __launch_bounds__(256) void bn_reduce(
    const float* __restrict__ partS, const float* __restrict__ partQ,
    float* __restrict__ bnsum, float* __restrict__ bnsq, int nParts) {
    __shared__ float rs[256], rq[256];
    int b = blockIdx.x, t = threadIdx.x;
    float S = 0.f, Q = 0.f;
    for (int p = t; p < nParts; p += 256) {
        S += partS[p * 64 + b];
        Q += partQ[p * 64 + b];
    }
    rs[t] = S; rq[t] = Q;
    __syncthreads();
    for (int off = 128; off > 0; off >>= 1) {
        if (t < off) { rs[t] += rs[t + off]; rq[t] += rq[t + off]; }
        __syncthreads();
    }
    if (t == 0) { bnsum[b] = rs[0]; bnsq[b] = rq[0]; }
}

// ---- BN apply + mean-pool + output matmul (batch sorted; zero atomics) ----
__device__ __forceinline__ int lowb(const int* __restrict__ a, int n, int v) {
    int lo = 0, hi = n;
    while (lo < hi) {
        int m = (lo + hi) >> 1;
        if (a[m] < v) lo = m + 1; else hi = m;
    }
    return lo;
}

__global__ __launch_bounds__(256) void bn_pool_out(
    const unsigned short* __restrict__ h, const int* __restrict__ batch,
    const float* __restrict__ bnsum, const float* __restrict__ bnsq,
    const float* __restrict__ gamma, const float* __restrict__ beta,
    const float* __restrict__ wout, const float* __restrict__ bout,
    float* __restrict__ out, int N) {
    __shared__ float sc[64], sh[64];
    __shared__ float part[4][64];
    __shared__ float gr[64];
    __shared__ int range[2];
    int g = blockIdx.x, t = threadIdx.x;
    if (t < 64) {
        float mu = bnsum[t] / (float)N;
        float var = bnsq[t] / (float)N - mu * mu;
        float s = gamma[t] * rsqrtf(var + 1e-5f);
        sc[t] = s;
        sh[t] = beta[t] - mu * s;
    }
    if (t == 64) range[0] = lowb(batch, N, g);
    if (t == 65) range[1] = lowb(batch, N, g + 1);
    __syncthreads();
    int s0 = range[0], s1 = range[1];
    int col = t & 63, ro = t >> 6;
    float acc = 0.f;
    for (int n = s0 + ro; n < s1; n += 4) {
        float v = __uint_as_float(((unsigned)h[(size_t)n * 64 + col]) << 16);
        acc += fmaxf(v * sc[col] + sh[col], 0.f);
    }
    part[ro][col] = acc;
    __syncthreads();
    if (t < 64) {
        float S = part[0][t] + part[1][t] + part[2][t] + part[3][t];
        float c = (float)(s1 - s0);
        gr[t] = (c > 0.f) ? S / c : 0.f;
    }
    __syncthreads();
    if (t < 64) {
        float a = bout[t];
        for (int f = 0; f < 64; f++) a += gr[f] * wout[f * 64 + t];
        out[g * 64 + t] = a;
    }
}

extern "C" void kernel_launch(void* const* d_in, const int* in_sizes, int n_in,
                              void* d_out, int out_size, void* d_ws, size_t ws_size,
                              hipStream_t stream) {
    const float* x     = (const float*)d_in[0];
    const int*   ei    = (const int*)d_in[1];
    const int*   batch = (const int*)d_in[2];
    const float* w1_0  = (const float*)d_in[3];
    const float* w1_r  = (const float*)d_in[4];
    const float* b1    = (const float*)d_in[5];
    const float* w2    = (const float*)d_in[6];
    const float* b2    = (const float*)d_in[7];
    const float* gamma = (const float*)d_in[8];
    const float* beta  = (const float*)d_in[9];
    const float* wout  = (const float*)d_in[10];
    const float* bout  = (const float*)d_in[11];
    float* out = (float*)d_out;

    const int N = in_sizes[2];               // 100000
    const int E = in_sizes[1] / 2;           // 3200000
    const int NB = (N + 127) >> 7;           // 782 buckets
    const int nblk = (E + CHUNK - 1) / CHUNK;// 391 scatter blocks
    const int nTiles = (N + 63) >> 6;        // 1563 layer tiles

    // Workspace (~58 MB)
    unsigned short* hbX = (unsigned short*)d_ws;             // N*64 bf16
    unsigned short* hbY = hbX + (size_t)N * 64;              // N*64 bf16
    int* bucketed2 = (int*)(hbY + (size_t)N * 64);           // nblk*CHUNK
    int* offsTab   = bucketed2 + (size_t)nblk * CHUNK;       // nblk*1025
    int* csrOut    = offsTab + (size_t)nblk * 1025;          // NB*CAP
    int* rowstart  = csrOut + (size_t)NB * CAP;              // N
    int* rowend    = rowstart + N;                           // N
    float* bnstats = (float*)(rowend + N);                   // 6*64
    float* partS   = bnstats + 384;                          // nTiles*64
    float* partQ   = partS + (size_t)nTiles * 64;            // nTiles*64
    unsigned short* w1T0 = (unsigned short*)(partQ + (size_t)nTiles * 64); // 64*32
    unsigned short* w1T  = w1T0 + 64 * 32;                   // 2*64*64
    unsigned short* w2T  = w1T + 2 * 64 * 64;                // 3*64*64

    const int* srcv = ei;
    const int* dstv = ei + E;

    prep_weights<<<48, 256, 0, stream>>>(w1_0, w1_r, w2, w1T0, w1T, w2T);

    // --- CSR build ---
    scatter_sort<<<nblk, 512, 0, stream>>>(srcv, dstv, bucketed2, offsTab, E);
    bucket_csr<<<NB, 256, 0, stream>>>(bucketed2, offsTab, csrOut, rowstart, rowend, N, nblk);

    // --- Layer 0 (fused agg3 + MLP) ---
    gin_layer<true><<<nTiles, 512, 0, stream>>>(x, rowstart, rowend, csrOut,
                                                nullptr, nullptr, nullptr, nullptr,
                                                (const uint4*)w1T0, b1,
                                                (const uint4*)w2T, b2,
                                                (uint4*)hbX, partS, partQ, N);
    bn_reduce<<<64, 256, 0, stream>>>(partS, partQ, bnstats, bnstats + 64, nTiles);

    // --- Layer 1 (fused BN0+agg + MLP) ---
    gin_layer<false><<<nTiles, 512, 0, stream>>>(hbX, rowstart, rowend, csrOut,
                                                 bnstats, bnstats + 64, gamma, beta,
                                                 (const uint4*)w1T, b1 + 64,
                                                 (const uint4*)(w2T + 4096), b2 + 64,
                                                 (uint4*)hbY, partS, partQ, N);
    bn_reduce<<<64, 256, 0, stream>>>(partS, partQ, bnstats + 128, bnstats + 192, nTiles);

    // --- Layer 2 (fused BN1+agg + MLP) ---
    gin_layer<false><<<nTiles, 512, 0, stream>>>(hbY, rowstart, rowend, csrOut,
                                                 bnstats + 128, bnstats + 192,
                                                 gamma + 64, beta + 64,
                                                 (const uint4*)(w1T + 4096), b1 + 128,
                                                 (const uint4*)(w2T + 8192), b2 + 128,
                                                 (uint4*)hbX, partS, partQ, N);
    bn_reduce<<<64, 256, 0, stream>>>(partS, partQ, bnstats + 256, bnstats + 320, nTiles);

    // --- BN2 apply + pool + output matmul ---
    bn_pool_out<<<512, 256, 0, stream>>>(hbX, batch, bnstats + 256, bnstats + 320,
                                         gamma + 128, beta + 128, wout, bout, out, N);
}

// Round 18
// 354.056 us; speedup vs baseline: 1.2223x; 1.0679x over previous
//
#include <hip/hip_runtime.h>

// GIN encoder: N=100k, E=3.2M, G=512, H=64, L=3.
// Round 18: fused layer with R14-agg scheduling geometry. 32-node tile,
// 256 threads, ~12KB LDS -> 8 blocks/CU, short-lived blocks, barrier
// stragglers hold only 4 waves (R17's 512-thr/23KB blocks throttled the
// gather to 2.08 TB/s vs standalone agg's 2.86). Gather: 8 lanes/node,
// 1 uint4/edge (verified shape). MFMA: 4 waves x 1 col-group x 2 row-groups.
// Output staged via freed acts buffer (3 syncs). scatter_sort, bucket_csr v3,
// bn_reduce v2, bn_pool_out unchanged from R14/R17 (377us).

#define NBMAX 1024
#define CAP 4608
#define CHUNK 8192
#define NBLK_MAX 512
#define MSTR 72   // LDS row stride in shorts (9 uint4, bank-staggered)

typedef __attribute__((ext_vector_type(8))) short bf16x8;
typedef __attribute__((ext_vector_type(4))) float f32x4;

static __device__ __forceinline__ bf16x8 as_bf16x8(uint4 u) {
    union { uint4 a; bf16x8 b; } x; x.a = u; return x.b;
}
static __device__ __forceinline__ unsigned short bf16r(float v) {
    unsigned u = __float_as_uint(v);
    return (unsigned short)((u + 0x7FFFu + ((u >> 16) & 1u)) >> 16);
}
static __device__ __forceinline__ unsigned bf16pack2(float a, float b) {
    return (unsigned)bf16r(a) | ((unsigned)bf16r(b) << 16);
}

// ---- weight prep: bf16, transposed to [col][k] ----
__global__ void prep_weights(const float* __restrict__ w1_0, const float* __restrict__ w1_r,
                             const float* __restrict__ w2, unsigned short* __restrict__ w1T0,
                             unsigned short* __restrict__ w1T, unsigned short* __restrict__ w2T) {
    int t = blockIdx.x * 256 + threadIdx.x;
    if (t < 64 * 32) {
        int c = t >> 5, k = t & 31;
        w1T0[t] = bf16r(k < 3 ? w1_0[k * 64 + c] : 0.f);
    }
    if (t < 2 * 64 * 64) {
        int l = t >> 12, r = t & 4095, c = r >> 6, k = r & 63;
        w1T[t] = bf16r(w1_r[l * 4096 + k * 64 + c]);
    }
    if (t < 3 * 64 * 64) {
        int l = t >> 12, r = t & 4095, c = r >> 6, k = r & 63;
        w2T[t] = bf16r(w2[l * 4096 + k * 64 + c]);
    }
}

// ---- scatter_sort: block counting-sorts its 8192-edge chunk by bucket ----
__global__ __launch_bounds__(512) void scatter_sort(
    const int* __restrict__ src, const int* __restrict__ dst,
    int* __restrict__ bucketed2, int* __restrict__ offsTab, int E) {
    __shared__ int hist[NBMAX];
    __shared__ int offs[NBMAX];
    __shared__ int stage[CHUNK];
    int t = threadIdx.x, blk = blockIdx.x;
    int e0 = blk * CHUNK, e1 = min(e0 + CHUNK, E);
    int len = e1 - e0;
    hist[t] = 0; hist[t + 512] = 0;
    __syncthreads();
    for (int e = e0 + t; e < e1; e += 512) atomicAdd(&hist[dst[e] >> 7], 1);
    __syncthreads();
    offs[t] = hist[t]; offs[t + 512] = hist[t + 512];
    __syncthreads();
    for (int off = 1; off < 1024; off <<= 1) {
        int v0 = (t >= off) ? offs[t - off] : 0;
        int v1 = offs[t + 512 - off];
        __syncthreads();
        offs[t] += v0;
        offs[t + 512] += v1;
        __syncthreads();
    }
    offs[t] -= hist[t]; offs[t + 512] -= hist[t + 512];
    hist[t] = 0; hist[t + 512] = 0;
    __syncthreads();
    offsTab[blk * 1025 + t] = offs[t];
    offsTab[blk * 1025 + t + 512] = offs[t + 512];
    if (t == 0) offsTab[blk * 1025 + 1024] = len;
    for (int e = e0 + t; e < e1; e += 512) {
        int d = dst[e];
        int bk = d >> 7;
        int r = offs[bk] + atomicAdd(&hist[bk], 1);
        stage[r] = src[e] | ((d & 127) << 20);
    }
    __syncthreads();
    for (int j = t; j < len; j += 512) bucketed2[e0 + j] = stage[j];
}

// ---- bucket_csr v3: binsearch run-gather, counting sort by src-block, then
// by row -> CSR with ~src-ascending rows (L2 locality for agg) ----
__global__ __launch_bounds__(256) void bucket_csr(
    const int* __restrict__ bucketed2, const int* __restrict__ offsTab,
    int* __restrict__ csrOut, int* __restrict__ rowstart, int* __restrict__ rowend,
    int N, int nblk) {
    __shared__ int ein[CAP];
    __shared__ int emid[CAP];
    __shared__ int runs[NBLK_MAX];
    __shared__ int rbeg[NBLK_MAX];
    __shared__ int hist[128];
    __shared__ int base[129];
    int b = blockIdx.x, t = threadIdx.x, node0 = b << 7;
    for (int r = t; r < NBLK_MAX; r += 256) {
        int l = 0, g0 = 0;
        if (r < nblk) {
            int beg = offsTab[r * 1025 + b];
            int end = offsTab[r * 1025 + b + 1];
            l = end - beg;
            g0 = r * CHUNK + beg;
        }
        runs[r] = l;
        rbeg[r] = g0;
    }
    __syncthreads();
    for (int off = 1; off < NBLK_MAX; off <<= 1) {
        int v0 = (t >= off) ? runs[t - off] : 0;
        int v1 = (t + 256 >= off) ? runs[t + 256 - off] : 0;
        __syncthreads();
        runs[t] += v0;
        runs[t + 256] += v1;
        __syncthreads();
    }
    int cnt = min(runs[NBLK_MAX - 1], CAP);
    for (int j = t; j < cnt; j += 256) {
        int lo = 0, hi = nblk - 1;
        while (lo < hi) {
            int m = (lo + hi) >> 1;
            if (runs[m] > j) hi = m; else lo = m + 1;
        }
        int st = lo ? runs[lo - 1] : 0;
        ein[j] = bucketed2[rbeg[lo] + (j - st)];
    }
    // pass 1: group by src block (src>>10)
    if (t < 128) hist[t] = 0;
    __syncthreads();
    for (int j = t; j < cnt; j += 256) atomicAdd(&hist[(ein[j] & 0xFFFFF) >> 10], 1);
    __syncthreads();
    if (t < 128) base[t + 1] = hist[t];
    if (t == 0) base[0] = 0;
    __syncthreads();
    for (int off = 1; off < 128; off <<= 1) {
        int v = 0;
        if (t < 128 && (t + 1) > off) v = base[t + 1 - off];
        __syncthreads();
        if (t < 128 && (t + 1) > off) base[t + 1] += v;
        __syncthreads();
    }
    if (t < 128) hist[t] = 0;
    __syncthreads();
    for (int j = t; j < cnt; j += 256) {
        int p = ein[j];
        int sb = (p & 0xFFFFF) >> 10;
        int pos = base[sb] + atomicAdd(&hist[sb], 1);
        emid[pos] = p;
    }
    __syncthreads();
    // pass 2: counting sort by row
    if (t < 128) hist[t] = 0;
    __syncthreads();
    for (int j = t; j < cnt; j += 256) atomicAdd(&hist[emid[j] >> 20], 1);
    __syncthreads();
    if (t < 128) base[t + 1] = hist[t];
    if (t == 0) base[0] = 0;
    __syncthreads();
    for (int off = 1; off < 128; off <<= 1) {
        int v = 0;
        if (t < 128 && (t + 1) > off) v = base[t + 1 - off];
        __syncthreads();
        if (t < 128 && (t + 1) > off) base[t + 1] += v;
        __syncthreads();
    }
    if (t < 128) {
        int n = node0 + t;
        if (n < N) {
            rowstart[n] = b * CAP + base[t];
            rowend[n] = b * CAP + base[t + 1];
        }
        hist[t] = 0;
    }
    __syncthreads();
    for (int j = t; j < cnt; j += 256) {
        int p = emid[j];
        int local = p >> 20;
        int pos = base[local] + atomicAdd(&hist[local], 1);
        ein[pos] = p & 0xFFFFF;
    }
    __syncthreads();
    for (int j = t; j < cnt; j += 256) csrOut[b * CAP + j] = ein[j];
}

// bf16x2-packed accumulate of relu(v*sc+sh)
__device__ __forceinline__ void accum_bf16(const uint4 u,
                                           const float4 scA, const float4 scB,
                                           const float4 shA, const float4 shB,
                                           float* __restrict__ a) {
    a[0] += fmaxf(__uint_as_float(u.x << 16) * scA.x + shA.x, 0.f);
    a[1] += fmaxf(__uint_as_float(u.x & 0xFFFF0000u) * scA.y + shA.y, 0.f);
    a[2] += fmaxf(__uint_as_float(u.y << 16) * scA.z + shA.z, 0.f);
    a[3] += fmaxf(__uint_as_float(u.y & 0xFFFF0000u) * scA.w + shA.w, 0.f);
    a[4] += fmaxf(__uint_as_float(u.z << 16) * scB.x + shB.x, 0.f);
    a[5] += fmaxf(__uint_as_float(u.z & 0xFFFF0000u) * scB.y + shB.y, 0.f);
    a[6] += fmaxf(__uint_as_float(u.w << 16) * scB.z + shB.z, 0.f);
    a[7] += fmaxf(__uint_as_float(u.w & 0xFFFF0000u) * scB.w + shB.w, 0.f);
}

// ---- fused GIN layer v4: 256 threads, 32-node tile (grid 3125).
// gather: 8 lanes/node (agg64_bn geometry); MFMA: wave w = col-group w*16,
// row-groups 0..1. Output staged via acts (freed after GEMM1). ----
template <bool L0>
__global__ __launch_bounds__(256) void gin_layer(
    const void* __restrict__ actInRaw,      // L0: float* x (d=3); else uint4* h
    const int* __restrict__ rowstart, const int* __restrict__ rowend,
    const int* __restrict__ csr,
    const float* __restrict__ bnsumPrev, const float* __restrict__ bnsqPrev,
    const float* __restrict__ gammaPrev, const float* __restrict__ betaPrev,
    const uint4* __restrict__ w1Tu, const float* __restrict__ b1,
    const uint4* __restrict__ w2Tu, const float* __restrict__ b2,
    uint4* __restrict__ houtU4,
    float* __restrict__ partS, float* __restrict__ partQ, int N) {
    __shared__ __align__(16) unsigned short acts[32 * MSTR];  // 4.5KB
    __shared__ __align__(16) unsigned short mids[32 * MSTR];  // 4.5KB
    __shared__ float red[8][64];                              // 2KB
    __shared__ float scs[64], shs[64];
    int t = threadIdx.x;
    int tileBase = blockIdx.x * 32;
    uint4* actsU4 = (uint4*)acts;
    const uint4* midU4 = (const uint4*)mids;
    const uint4 z4 = make_uint4(0, 0, 0, 0);

    if (!L0) {
        if (t < 64) {
            float mu = bnsumPrev[t] / (float)N;
            float var = bnsqPrev[t] / (float)N - mu * mu;
            float s = gammaPrev[t] * rsqrtf(var + 1e-5f);
            scs[t] = s;
            shs[t] = betaPrev[t] - mu * s;
        }
        __syncthreads();
    }

    // ---- gather phase: node = t>>3 (0..31), slice l = t&7 ----
    {
        int ni = t >> 3, l = t & 7;
        int n = tileBase + ni;
        if (L0) {
            const float* x = (const float*)actInRaw;
            uint4 o = z4;
            if (l == 0 && n < N) {
                float s0 = x[n * 3], s1 = x[n * 3 + 1], s2 = x[n * 3 + 2];
                float b0 = 0.f, b1v = 0.f, b2v = 0.f;
                float c0 = 0.f, c1 = 0.f, c2 = 0.f;
                float d0 = 0.f, d1 = 0.f, d2 = 0.f;
                int s = rowstart[n], e = rowend[n];
                int j = s;
                for (; j + 3 < e; j += 4) {
                    int i0 = csr[j], i1 = csr[j + 1], i2 = csr[j + 2], i3 = csr[j + 3];
                    s0 += x[i0 * 3]; s1 += x[i0 * 3 + 1]; s2 += x[i0 * 3 + 2];
                    b0 += x[i1 * 3]; b1v += x[i1 * 3 + 1]; b2v += x[i1 * 3 + 2];
                    c0 += x[i2 * 3]; c1 += x[i2 * 3 + 1]; c2 += x[i2 * 3 + 2];
                    d0 += x[i3 * 3]; d1 += x[i3 * 3 + 1]; d2 += x[i3 * 3 + 2];
                }
                for (; j < e; j++) {
                    int nb = csr[j];
                    s0 += x[nb * 3]; s1 += x[nb * 3 + 1]; s2 += x[nb * 3 + 2];
                }
                s0 += b0 + c0 + d0; s1 += b1v + c1 + d1; s2 += b2v + c2 + d2;
                o = make_uint4(bf16pack2(s0, s1), bf16pack2(s2, 0.f), 0u, 0u);
            }
            actsU4[ni * 9 + l] = o;
        } else {
            const uint4* hr = (const uint4*)actInRaw;
            int c0i = l * 8;
            float4 scA = *(const float4*)&scs[c0i], scB = *(const float4*)&scs[c0i + 4];
            float4 shA = *(const float4*)&shs[c0i], shB = *(const float4*)&shs[c0i + 4];
            float A[8] = {0,0,0,0,0,0,0,0};
            float B[8] = {0,0,0,0,0,0,0,0};
            if (n < N) {
                accum_bf16(hr[(size_t)n * 8 + l], scA, scB, shA, shB, A);  // self
                int s = rowstart[n], e = rowend[n];
                int j = s;
                for (; j + 3 < e; j += 4) {
                    int i0 = csr[j], i1 = csr[j + 1], i2 = csr[j + 2], i3 = csr[j + 3];
                    uint4 w0 = hr[(size_t)i0 * 8 + l];
                    uint4 w1 = hr[(size_t)i1 * 8 + l];
                    uint4 w2 = hr[(size_t)i2 * 8 + l];
                    uint4 w3 = hr[(size_t)i3 * 8 + l];
                    accum_bf16(w0, scA, scB, shA, shB, A);
                    accum_bf16(w1, scA, scB, shA, shB, B);
                    accum_bf16(w2, scA, scB, shA, shB, A);
                    accum_bf16(w3, scA, scB, shA, shB, B);
                }
                for (; j < e; j++) {
                    uint4 w = hr[(size_t)csr[j] * 8 + l];
                    accum_bf16(w, scA, scB, shA, shB, A);
                }
            }
            uint4 o;
            o.x = bf16pack2(A[0] + B[0], A[1] + B[1]);
            o.y = bf16pack2(A[2] + B[2], A[3] + B[3]);
            o.z = bf16pack2(A[4] + B[4], A[5] + B[5]);
            o.w = bf16pack2(A[6] + B[6], A[7] + B[7]);
            actsU4[ni * 9 + l] = o;
        }
    }

    // ---- MFMA phase: wave w -> col-group w*16, row-groups 0..1 ----
    int w = t >> 6, l64 = t & 63, m16 = l64 & 15, q = l64 >> 4;
    int col = w * 16 + m16;
    bf16x8 w1f0, w1f1, w2f0, w2f1;
    float bias1 = b1[col], bias2 = b2[col];
    if (L0) {
        w1f0 = as_bf16x8(w1Tu[col * 4 + q]);
    } else {
        w1f0 = as_bf16x8(w1Tu[col * 8 + q]);
        w1f1 = as_bf16x8(w1Tu[col * 8 + 4 + q]);
    }
    w2f0 = as_bf16x8(w2Tu[col * 8 + q]);
    w2f1 = as_bf16x8(w2Tu[col * 8 + 4 + q]);
    __syncthreads();  // S1: acts ready
#pragma unroll
    for (int rg = 0; rg < 2; rg++) {
        int rloc = rg * 16 + m16;
        bf16x8 a0 = as_bf16x8(actsU4[rloc * 9 + q]);
        f32x4 acc = {bias1, bias1, bias1, bias1};
        if (L0) {
            acc = __builtin_amdgcn_mfma_f32_16x16x32_bf16(a0, w1f0, acc, 0, 0, 0);
        } else {
            bf16x8 a1 = as_bf16x8(actsU4[rloc * 9 + 4 + q]);
            acc = __builtin_amdgcn_mfma_f32_16x16x32_bf16(a0, w1f0, acc, 0, 0, 0);
            acc = __builtin_amdgcn_mfma_f32_16x16x32_bf16(a1, w1f1, acc, 0, 0, 0);
        }
#pragma unroll
        for (int r = 0; r < 4; r++) {
            int row = rg * 16 + q * 4 + r;
            mids[row * MSTR + col] = bf16r(fmaxf(acc[r], 0.f));
        }
    }
    __syncthreads();  // S2: mids ready
    f32x4 accs[2];
#pragma unroll
    for (int rg = 0; rg < 2; rg++) {
        int rloc = rg * 16 + m16;
        bf16x8 a20 = as_bf16x8(midU4[rloc * 9 + q]);
        bf16x8 a21 = as_bf16x8(midU4[rloc * 9 + 4 + q]);
        f32x4 acc = {bias2, bias2, bias2, bias2};
        acc = __builtin_amdgcn_mfma_f32_16x16x32_bf16(a20, w2f0, acc, 0, 0, 0);
        acc = __builtin_amdgcn_mfma_f32_16x16x32_bf16(a21, w2f1, acc, 0, 0, 0);
        accs[rg] = acc;
    }
    // stage output into acts (all GEMM1 reads of acts ended before S2)
    float sA = 0.f, sB = 0.f, qA = 0.f, qB = 0.f;
#pragma unroll
    for (int rg = 0; rg < 2; rg++) {
#pragma unroll
        for (int r = 0; r < 4; r++) {
            int row = rg * 16 + q * 4 + r;
            float v = accs[rg][r];
            if (tileBase + row < N) {
                if (rg == 0) { sA += v; qA += v * v; } else { sB += v; qB += v * v; }
            }
            acts[row * MSTR + col] = bf16r(v);
        }
    }
    __syncthreads();  // S3: output staged
    // coalesced store: 32 rows x 8 uint4 = 256, one per thread
    {
        int row = t >> 3, qo = t & 7;
        int gr = tileBase + row;
        if (gr < N) houtU4[(size_t)gr * 8 + qo] = actsU4[row * 9 + qo];
    }
    // BN partials: red[rg*4+q][col], disjoint per (q,col)
    red[q][col] = sA;
    red[4 + q][col] = sB;
    __syncthreads();
    if (t < 64) {
        float S = 0.f;
        for (int i = 0; i < 8; i++) S += red[i][t];
        partS[blockIdx.x * 64 + t] = S;
    }
    __syncthreads();
    red[q][col] = qA;
    red[4 + q][col] = qB;
    __syncthreads();
    if (t < 64) {
        float S = 0.f;
        for (int i = 0; i < 8; i++) S += red[i][t];
        partQ[blockIdx.x * 64 + t] = S;
    }
}

// ---- bn_reduce v2: 64 blocks, block b reduces column b over nParts ----
__global__ __launch_bounds__(256) void bn_reduce(
    const float* __restrict__ partS, const float* __restrict__ partQ,
    float* __restrict__ bnsum, float* __restrict__ bnsq, int nParts) {
    __shared__ float rs[256], rq[256];
    int b = blockIdx.x, t = threadIdx.x;
    float S = 0.f, Q = 0.f;
    for (int p = t; p < nParts; p += 256) {
        S += partS[p * 64 + b];
        Q += partQ[p * 64 + b];
    }
    rs[t] = S; rq[t] = Q;
    __syncthreads();
    for (int off = 128; off > 0; off >>= 1) {
        if (t < off) { rs[t] += rs[t + off]; rq[t] += rq[t + off]; }
        __syncthreads();
    }
    if (t == 0) { bnsum[b] = rs[0]; bnsq[b] = rq[0]; }
}

// ---- BN apply + mean-pool + output matmul (batch sorted; zero atomics) ----
__device__ __forceinline__ int lowb(const int* __restrict__ a, int n, int v) {
    int lo = 0, hi = n;
    while (lo < hi) {
        int m = (lo + hi) >> 1;
        if (a[m] < v) lo = m + 1; else hi = m;
    }
    return lo;
}

__global__ __launch_bounds__(256) void bn_pool_out(
    const unsigned short* __restrict__ h, const int* __restrict__ batch,
    const float* __restrict__ bnsum, const float* __restrict__ bnsq,
    const float* __restrict__ gamma, const float* __restrict__ beta,
    const float* __restrict__ wout, const float* __restrict__ bout,
    float* __restrict__ out, int N) {
    __shared__ float sc[64], sh[64];
    __shared__ float part[4][64];
    __shared__ float gr[64];
    __shared__ int range[2];
    int g = blockIdx.x, t = threadIdx.x;
    if (t < 64) {
        float mu = bnsum[t] / (float)N;
        float var = bnsq[t] / (float)N - mu * mu;
        float s = gamma[t] * rsqrtf(var + 1e-5f);
        sc[t] = s;
        sh[t] = beta[t] - mu * s;
    }
    if (t == 64) range[0] = lowb(batch, N, g);
    if (t == 65) range[1] = lowb(batch, N, g + 1);
    __syncthreads();
    int s0 = range[0], s1 = range[1];
    int col = t & 63, ro = t >> 6;
    float acc = 0.f;
    for (int n = s0 + ro; n < s1; n += 4) {
        float v = __uint_as_float(((unsigned)h[(size_t)n * 64 + col]) << 16);
        acc += fmaxf(v * sc[col] + sh[col], 0.f);
    }
    part[ro][col] = acc;
    __syncthreads();
    if (t < 64) {
        float S = part[0][t] + part[1][t] + part[2][t] + part[3][t];
        float c = (float)(s1 - s0);
        gr[t] = (c > 0.f) ? S / c : 0.f;
    }
    __syncthreads();
    if (t < 64) {
        float a = bout[t];
        for (int f = 0; f < 64; f++) a += gr[f] * wout[f * 64 + t];
        out[g * 64 + t] = a;
    }
}

extern "C" void kernel_launch(void* const* d_in, const int* in_sizes, int n_in,
                              void* d_out, int out_size, void* d_ws, size_t ws_size,
                              hipStream_t stream) {
    const float* x     = (const float*)d_in[0];
    const int*   ei    = (const int*)d_in[1];
    const int*   batch = (const int*)d_in[2];
    const float* w1_0  = (const float*)d_in[3];
    const float* w1_r  = (const float*)d_in[4];
    const float* b1    = (const float*)d_in[5];
    const float* w2    = (const float*)d_in[6];
    const float* b2    = (const float*)d_in[7];
    const float* gamma = (const float*)d_in[8];
    const float* beta  = (const float*)d_in[9];
    const float* wout  = (const float*)d_in[10];
    const float* bout  = (const float*)d_in[11];
    float* out = (float*)d_out;

    const int N = in_sizes[2];               // 100000
    const int E = in_sizes[1] / 2;           // 3200000
    const int NB = (N + 127) >> 7;           // 782 buckets
    const int nblk = (E + CHUNK - 1) / CHUNK;// 391 scatter blocks
    const int nT32 = (N + 31) >> 5;          // 3125 layer tiles (exact: N=3125*32)

    // Workspace (~60 MB)
    unsigned short* hbX = (unsigned short*)d_ws;             // N*64 bf16
    unsigned short* hbY = hbX + (size_t)N * 64;              // N*64 bf16
    int* bucketed2 = (int*)(hbY + (size_t)N * 64);           // nblk*CHUNK
    int* offsTab   = bucketed2 + (size_t)nblk * CHUNK;       // nblk*1025
    int* csrOut    = offsTab + (size_t)nblk * 1025;          // NB*CAP
    int* rowstart  = csrOut + (size_t)NB * CAP;              // N
    int* rowend    = rowstart + N;                           // N
    float* bnstats = (float*)(rowend + N);                   // 6*64
    float* partS   = bnstats + 384;                          // nT32*64
    float* partQ   = partS + (size_t)nT32 * 64;              // nT32*64
    unsigned short* w1T0 = (unsigned short*)(partQ + (size_t)nT32 * 64); // 64*32
    unsigned short* w1T  = w1T0 + 64 * 32;                   // 2*64*64
    unsigned short* w2T  = w1T + 2 * 64 * 64;                // 3*64*64

    const int* srcv = ei;
    const int* dstv = ei + E;

    prep_weights<<<48, 256, 0, stream>>>(w1_0, w1_r, w2, w1T0, w1T, w2T);

    // --- CSR build ---
    scatter_sort<<<nblk, 512, 0, stream>>>(srcv, dstv, bucketed2, offsTab, E);
    bucket_csr<<<NB, 256, 0, stream>>>(bucketed2, offsTab, csrOut, rowstart, rowend, N, nblk);

    // --- Layer 0 (fused agg3 + MLP) ---
    gin_layer<true><<<nT32, 256, 0, stream>>>(x, rowstart, rowend, csrOut,
                                              nullptr, nullptr, nullptr, nullptr,
                                              (const uint4*)w1T0, b1,
                                              (const uint4*)w2T, b2,
                                              (uint4*)hbX, partS, partQ, N);
    bn_reduce<<<64, 256, 0, stream>>>(partS, partQ, bnstats, bnstats + 64, nT32);

    // --- Layer 1 (fused BN0+agg + MLP) ---
    gin_layer<false><<<nT32, 256, 0, stream>>>(hbX, rowstart, rowend, csrOut,
                                               bnstats, bnstats + 64, gamma, beta,
                                               (const uint4*)w1T, b1 + 64,
                                               (const uint4*)(w2T + 4096), b2 + 64,
                                               (uint4*)hbY, partS, partQ, N);
    bn_reduce<<<64, 256, 0, stream>>>(partS, partQ, bnstats + 128, bnstats + 192, nT32);

    // --- Layer 2 (fused BN1+agg + MLP) ---
    gin_layer<false><<<nT32, 256, 0, stream>>>(hbY, rowstart, rowend, csrOut,
                                               bnstats + 128, bnstats + 192,
                                               gamma + 64, beta + 64,
                                               (const uint4*)(w1T + 4096), b1 + 128,
                                               (const uint4*)(w2T + 8192), b2 + 128,
                                               (uint4*)hbX, partS, partQ, N);
    bn_reduce<<<64, 256, 0, stream>>>(partS, partQ, bnstats + 256, bnstats + 320, nT32);

    // --- BN2 apply + pool + output matmul ---
    bn_pool_out<<<512, 256, 0, stream>>>(hbX, batch, bnstats + 256, bnstats + 320,
                                         gamma + 128, beta + 128, wout, bout, out, N);
}

// Round 19
// 345.438 us; speedup vs baseline: 1.2528x; 1.0249x over previous
//
#include <hip/hip_runtime.h>

// GIN encoder: N=100k, E=3.2M, G=512, H=64, L=3.
// Round 19 (R18 = 354us base):
//  - scatter_sort / bucket_csr: barrier scans replaced by wave-level
//    __shfl_up scans (scatter 20->2 syncs, csr ~32->6).
//  - L0 gather uses all 256 threads (8 row-segments/node, LDS combine);
//    R18 left 7/8 lanes idle for d=3.
//  - gin_layer L1/L2 (60us, 2.6 TB/s, within ~13% of gather floor) unchanged.

#define NBMAX 1024
#define CAP 4608
#define CHUNK 8192
#define NBLK_MAX 512
#define MSTR 72   // LDS row stride in shorts (9 uint4, bank-staggered)

typedef __attribute__((ext_vector_type(8))) short bf16x8;
typedef __attribute__((ext_vector_type(4))) float f32x4;

static __device__ __forceinline__ bf16x8 as_bf16x8(uint4 u) {
    union { uint4 a; bf16x8 b; } x; x.a = u; return x.b;
}
static __device__ __forceinline__ unsigned short bf16r(float v) {
    unsigned u = __float_as_uint(v);
    return (unsigned short)((u + 0x7FFFu + ((u >> 16) & 1u)) >> 16);
}
static __device__ __forceinline__ unsigned bf16pack2(float a, float b) {
    return (unsigned)bf16r(a) | ((unsigned)bf16r(b) << 16);
}

// ---- weight prep: bf16, transposed to [col][k] ----
__global__ void prep_weights(const float* __restrict__ w1_0, const float* __restrict__ w1_r,
                             const float* __restrict__ w2, unsigned short* __restrict__ w1T0,
                             unsigned short* __restrict__ w1T, unsigned short* __restrict__ w2T) {
    int t = blockIdx.x * 256 + threadIdx.x;
    if (t < 64 * 32) {
        int c = t >> 5, k = t & 31;
        w1T0[t] = bf16r(k < 3 ? w1_0[k * 64 + c] : 0.f);
    }
    if (t < 2 * 64 * 64) {
        int l = t >> 12, r = t & 4095, c = r >> 6, k = r & 63;
        w1T[t] = bf16r(w1_r[l * 4096 + k * 64 + c]);
    }
    if (t < 3 * 64 * 64) {
        int l = t >> 12, r = t & 4095, c = r >> 6, k = r & 63;
        w2T[t] = bf16r(w2[l * 4096 + k * 64 + c]);
    }
}

// ---- scatter_sort: chunk counting sort; wave-scan (2 syncs in scan path) ----
__global__ __launch_bounds__(512) void scatter_sort(
    const int* __restrict__ src, const int* __restrict__ dst,
    int* __restrict__ bucketed2, int* __restrict__ offsTab, int E) {
    __shared__ int hist[NBMAX];
    __shared__ int offs[NBMAX];
    __shared__ int stage[CHUNK];
    __shared__ int wsum8[8];
    int t = threadIdx.x, blk = blockIdx.x;
    int e0 = blk * CHUNK, e1 = min(e0 + CHUNK, E);
    int len = e1 - e0;
    hist[t] = 0; hist[t + 512] = 0;
    __syncthreads();
    for (int e = e0 + t; e < e1; e += 512) atomicAdd(&hist[dst[e] >> 7], 1);
    __syncthreads();
    // wave-level exclusive scan over 1024 bins (thread t owns bins 2t,2t+1)
    int h0 = hist[2 * t], h1 = hist[2 * t + 1];
    int pair = h0 + h1;
    int lane = t & 63;
    int incl = pair;
#pragma unroll
    for (int d = 1; d < 64; d <<= 1) {
        int up = __shfl_up(incl, d);
        if (lane >= d) incl += up;
    }
    if (lane == 63) wsum8[t >> 6] = incl;
    __syncthreads();
    int wid = t >> 6, wpre = 0;
    for (int i = 0; i < wid; i++) wpre += wsum8[i];
    int exclP = wpre + incl - pair;
    offs[2 * t] = exclP;
    offs[2 * t + 1] = exclP + h0;
    hist[2 * t] = 0; hist[2 * t + 1] = 0;  // reset as cursors
    __syncthreads();
    offsTab[blk * 1025 + t] = offs[t];
    offsTab[blk * 1025 + t + 512] = offs[t + 512];
    if (t == 0) offsTab[blk * 1025 + 1024] = len;
    for (int e = e0 + t; e < e1; e += 512) {
        int d = dst[e];
        int bk = d >> 7;
        int r = offs[bk] + atomicAdd(&hist[bk], 1);
        stage[r] = src[e] | ((d & 127) << 20);
    }
    __syncthreads();
    for (int j = t; j < len; j += 512) bucketed2[e0 + j] = stage[j];
}

// ---- bucket_csr v4: wave scans; binsearch run-gather; src-block then row
// counting sorts -> CSR with ~src-ascending rows ----
__global__ __launch_bounds__(256) void bucket_csr(
    const int* __restrict__ bucketed2, const int* __restrict__ offsTab,
    int* __restrict__ csrOut, int* __restrict__ rowstart, int* __restrict__ rowend,
    int N, int nblk) {
    __shared__ int ein[CAP];
    __shared__ int emid[CAP];
    __shared__ int runs[NBLK_MAX];
    __shared__ int rbeg[NBLK_MAX];
    __shared__ int hist[128];
    __shared__ int base[129];
    __shared__ int wsum4[4];
    __shared__ int wtot2[2];
    int b = blockIdx.x, t = threadIdx.x, node0 = b << 7;
    for (int r = t; r < NBLK_MAX; r += 256) {
        int l = 0, g0 = 0;
        if (r < nblk) {
            int beg = offsTab[r * 1025 + b];
            int end = offsTab[r * 1025 + b + 1];
            l = end - beg;
            g0 = r * CHUNK + beg;
        }
        runs[r] = l;
        rbeg[r] = g0;
    }
    __syncthreads();
    // wave scan over 512 runs (thread t owns 2t, 2t+1) -> inclusive in runs[]
    {
        int l0 = runs[2 * t], l1 = runs[2 * t + 1];
        int pair = l0 + l1;
        int lane = t & 63;
        int incl = pair;
#pragma unroll
        for (int d = 1; d < 64; d <<= 1) {
            int up = __shfl_up(incl, d);
            if (lane >= d) incl += up;
        }
        if (lane == 63) wsum4[t >> 6] = incl;
        __syncthreads();
        int wid = t >> 6, wpre = 0;
        for (int i = 0; i < wid; i++) wpre += wsum4[i];
        int exclP = wpre + incl - pair;
        runs[2 * t] = exclP + l0;
        runs[2 * t + 1] = exclP + l0 + l1;
    }
    __syncthreads();
    int cnt = min(runs[NBLK_MAX - 1], CAP);
    for (int j = t; j < cnt; j += 256) {
        int lo = 0, hi = nblk - 1;
        while (lo < hi) {
            int m = (lo + hi) >> 1;
            if (runs[m] > j) hi = m; else lo = m + 1;
        }
        int st = lo ? runs[lo - 1] : 0;
        ein[j] = bucketed2[rbeg[lo] + (j - st)];
    }
    // pass 1: group by src block (src>>10)
    if (t < 128) hist[t] = 0;
    __syncthreads();
    for (int j = t; j < cnt; j += 256) atomicAdd(&hist[(ein[j] & 0xFFFFF) >> 10], 1);
    __syncthreads();
    {
        int lane = t & 63;
        int hv = (t < 128) ? hist[t] : 0;
        int incl = hv;
#pragma unroll
        for (int d = 1; d < 64; d <<= 1) {
            int up = __shfl_up(incl, d);
            if (lane >= d) incl += up;
        }
        if (t < 128 && lane == 63) wtot2[t >> 6] = incl;
        __syncthreads();
        if (t >= 64 && t < 128) incl += wtot2[0];
        if (t < 128) { base[t + 1] = incl; hist[t] = 0; }
        if (t == 0) base[0] = 0;
    }
    __syncthreads();
    for (int j = t; j < cnt; j += 256) {
        int p = ein[j];
        int sb = (p & 0xFFFFF) >> 10;
        int pos = base[sb] + atomicAdd(&hist[sb], 1);
        emid[pos] = p;
    }
    __syncthreads();
    // pass 2: counting sort by row
    if (t < 128) hist[t] = 0;
    __syncthreads();
    for (int j = t; j < cnt; j += 256) atomicAdd(&hist[emid[j] >> 20], 1);
    __syncthreads();
    {
        int lane = t & 63;
        int hv = (t < 128) ? hist[t] : 0;
        int incl = hv;
#pragma unroll
        for (int d = 1; d < 64; d <<= 1) {
            int up = __shfl_up(incl, d);
            if (lane >= d) incl += up;
        }
        if (t < 128 && lane == 63) wtot2[t >> 6] = incl;
        __syncthreads();
        if (t >= 64 && t < 128) incl += wtot2[0];
        if (t < 128) { base[t + 1] = incl; hist[t] = 0; }
        if (t == 0) base[0] = 0;
    }
    __syncthreads();
    if (t < 128) {
        int n = node0 + t;
        if (n < N) {
            rowstart[n] = b * CAP + base[t];
            rowend[n] = b * CAP + base[t + 1];
        }
    }
    __syncthreads();
    for (int j = t; j < cnt; j += 256) {
        int p = emid[j];
        int local = p >> 20;
        int pos = base[local] + atomicAdd(&hist[local], 1);
        ein[pos] = p & 0xFFFFF;
    }
    __syncthreads();
    for (int j = t; j < cnt; j += 256) csrOut[b * CAP + j] = ein[j];
}

// bf16x2-packed accumulate of relu(v*sc+sh)
__device__ __forceinline__ void accum_bf16(const uint4 u,
                                           const float4 scA, const float4 scB,
                                           const float4 shA, const float4 shB,
                                           float* __restrict__ a) {
    a[0] += fmaxf(__uint_as_float(u.x << 16) * scA.x + shA.x, 0.f);
    a[1] += fmaxf(__uint_as_float(u.x & 0xFFFF0000u) * scA.y + shA.y, 0.f);
    a[2] += fmaxf(__uint_as_float(u.y << 16) * scA.z + shA.z, 0.f);
    a[3] += fmaxf(__uint_as_float(u.y & 0xFFFF0000u) * scA.w + shA.w, 0.f);
    a[4] += fmaxf(__uint_as_float(u.z << 16) * scB.x + shB.x, 0.f);
    a[5] += fmaxf(__uint_as_float(u.z & 0xFFFF0000u) * scB.y + shB.y, 0.f);
    a[6] += fmaxf(__uint_as_float(u.w << 16) * scB.z + shB.z, 0.f);
    a[7] += fmaxf(__uint_as_float(u.w & 0xFFFF0000u) * scB.w + shB.w, 0.f);
}

// ---- fused GIN layer v4.1: 256 threads, 32-node tile (grid 3125).
// L1/L2 gather: 8 lanes/node (verified R18). L0 gather: 8 row-segments/node
// (all threads active), combined via LDS. MFMA: wave w = col-group w*16. ----
template <bool L0>
__global__ __launch_bounds__(256) void gin_layer(
    const void* __restrict__ actInRaw,      // L0: float* x (d=3); else uint4* h
    const int* __restrict__ rowstart, const int* __restrict__ rowend,
    const int* __restrict__ csr,
    const float* __restrict__ bnsumPrev, const float* __restrict__ bnsqPrev,
    const float* __restrict__ gammaPrev, const float* __restrict__ betaPrev,
    const uint4* __restrict__ w1Tu, const float* __restrict__ b1,
    const uint4* __restrict__ w2Tu, const float* __restrict__ b2,
    uint4* __restrict__ houtU4,
    float* __restrict__ partS, float* __restrict__ partQ, int N) {
    __shared__ __align__(16) unsigned short acts[32 * MSTR];  // 4.5KB
    __shared__ __align__(16) unsigned short mids[32 * MSTR];  // 4.5KB
    __shared__ float red[8][64];                              // 2KB
    __shared__ float scs[64], shs[64];
    int t = threadIdx.x;
    int tileBase = blockIdx.x * 32;
    uint4* actsU4 = (uint4*)acts;
    const uint4* midU4 = (const uint4*)mids;
    const uint4 z4 = make_uint4(0, 0, 0, 0);

    if (!L0) {
        if (t < 64) {
            float mu = bnsumPrev[t] / (float)N;
            float var = bnsqPrev[t] / (float)N - mu * mu;
            float s = gammaPrev[t] * rsqrtf(var + 1e-5f);
            scs[t] = s;
            shs[t] = betaPrev[t] - mu * s;
        }
        __syncthreads();
    }

    // ---- gather phase ----
    if (L0) {
        // 8 segments per node row; all 256 threads active; stage in mids
        const float* x = (const float*)actInRaw;
        int ni = t & 31, seg = t >> 5;
        int n = tileBase + ni;
        float s0 = 0.f, s1 = 0.f, s2 = 0.f;
        if (n < N) {
            int srow = rowstart[n], erow = rowend[n];
            for (int j = srow + seg; j < erow; j += 8) {
                int nb = csr[j];
                s0 += x[nb * 3]; s1 += x[nb * 3 + 1]; s2 += x[nb * 3 + 2];
            }
            if (seg == 0) { s0 += x[n * 3]; s1 += x[n * 3 + 1]; s2 += x[n * 3 + 2]; }
        }
        float* stg = (float*)mids;  // 1152 floats available; need 768
        stg[seg * 96 + ni * 3 + 0] = s0;
        stg[seg * 96 + ni * 3 + 1] = s1;
        stg[seg * 96 + ni * 3 + 2] = s2;
        __syncthreads();
        if (t < 32) {
            float a0 = 0.f, a1 = 0.f, a2 = 0.f;
#pragma unroll
            for (int g2 = 0; g2 < 8; g2++) {
                a0 += stg[g2 * 96 + t * 3 + 0];
                a1 += stg[g2 * 96 + t * 3 + 1];
                a2 += stg[g2 * 96 + t * 3 + 2];
            }
            actsU4[t * 9] = make_uint4(bf16pack2(a0, a1), bf16pack2(a2, 0.f), 0u, 0u);
        }
    } else {
        const uint4* hr = (const uint4*)actInRaw;
        int ni = t >> 3, l = t & 7;
        int n = tileBase + ni;
        int c0i = l * 8;
        float4 scA = *(const float4*)&scs[c0i], scB = *(const float4*)&scs[c0i + 4];
        float4 shA = *(const float4*)&shs[c0i], shB = *(const float4*)&shs[c0i + 4];
        float A[8] = {0,0,0,0,0,0,0,0};
        float B[8] = {0,0,0,0,0,0,0,0};
        if (n < N) {
            accum_bf16(hr[(size_t)n * 8 + l], scA, scB, shA, shB, A);  // self
            int s = rowstart[n], e = rowend[n];
            int j = s;
            for (; j + 3 < e; j += 4) {
                int i0 = csr[j], i1 = csr[j + 1], i2 = csr[j + 2], i3 = csr[j + 3];
                uint4 w0 = hr[(size_t)i0 * 8 + l];
                uint4 w1 = hr[(size_t)i1 * 8 + l];
                uint4 w2 = hr[(size_t)i2 * 8 + l];
                uint4 w3 = hr[(size_t)i3 * 8 + l];
                accum_bf16(w0, scA, scB, shA, shB, A);
                accum_bf16(w1, scA, scB, shA, shB, B);
                accum_bf16(w2, scA, scB, shA, shB, A);
                accum_bf16(w3, scA, scB, shA, shB, B);
            }
            for (; j < e; j++) {
                uint4 w = hr[(size_t)csr[j] * 8 + l];
                accum_bf16(w, scA, scB, shA, shB, A);
            }
        }
        uint4 o;
        o.x = bf16pack2(A[0] + B[0], A[1] + B[1]);
        o.y = bf16pack2(A[2] + B[2], A[3] + B[3]);
        o.z = bf16pack2(A[4] + B[4], A[5] + B[5]);
        o.w = bf16pack2(A[6] + B[6], A[7] + B[7]);
        actsU4[ni * 9 + l] = o;
    }

    // ---- MFMA phase: wave w -> col-group w*16, row-groups 0..1 ----
    int w = t >> 6, l64 = t & 63, m16 = l64 & 15, q = l64 >> 4;
    int col = w * 16 + m16;
    bf16x8 w1f0, w1f1, w2f0, w2f1;
    float bias1 = b1[col], bias2 = b2[col];
    if (L0) {
        w1f0 = as_bf16x8(w1Tu[col * 4 + q]);
    } else {
        w1f0 = as_bf16x8(w1Tu[col * 8 + q]);
        w1f1 = as_bf16x8(w1Tu[col * 8 + 4 + q]);
    }
    w2f0 = as_bf16x8(w2Tu[col * 8 + q]);
    w2f1 = as_bf16x8(w2Tu[col * 8 + 4 + q]);
    __syncthreads();  // S1: acts ready (and L0 staging in mids fully consumed)
#pragma unroll
    for (int rg = 0; rg < 2; rg++) {
        int rloc = rg * 16 + m16;
        bf16x8 a0 = as_bf16x8(L0 ? (q == 0 ? actsU4[rloc * 9] : z4)
                                 : actsU4[rloc * 9 + q]);
        f32x4 acc = {bias1, bias1, bias1, bias1};
        if (L0) {
            acc = __builtin_amdgcn_mfma_f32_16x16x32_bf16(a0, w1f0, acc, 0, 0, 0);
        } else {
            bf16x8 a1 = as_bf16x8(actsU4[rloc * 9 + 4 + q]);
            acc = __builtin_amdgcn_mfma_f32_16x16x32_bf16(a0, w1f0, acc, 0, 0, 0);
            acc = __builtin_amdgcn_mfma_f32_16x16x32_bf16(a1, w1f1, acc, 0, 0, 0);
        }
#pragma unroll
        for (int r = 0; r < 4; r++) {
            int row = rg * 16 + q * 4 + r;
            mids[row * MSTR + col] = bf16r(fmaxf(acc[r], 0.f));
        }
    }
    __syncthreads();  // S2: mids ready
    f32x4 accs[2];
#pragma unroll
    for (int rg = 0; rg < 2; rg++) {
        int rloc = rg * 16 + m16;
        bf16x8 a20 = as_bf16x8(midU4[rloc * 9 + q]);
        bf16x8 a21 = as_bf16x8(midU4[rloc * 9 + 4 + q]);
        f32x4 acc = {bias2, bias2, bias2, bias2};
        acc = __builtin_amdgcn_mfma_f32_16x16x32_bf16(a20, w2f0, acc, 0, 0, 0);
        acc = __builtin_amdgcn_mfma_f32_16x16x32_bf16(a21, w2f1, acc, 0, 0, 0);
        accs[rg] = acc;
    }
    // stage output into acts (all GEMM1 reads of acts ended before S2)
    float sA = 0.f, sB = 0.f, qA = 0.f, qB = 0.f;
#pragma unroll
    for (int rg = 0; rg < 2; rg++) {
#pragma unroll
        for (int r = 0; r < 4; r++) {
            int row = rg * 16 + q * 4 + r;
            float v = accs[rg][r];
            if (tileBase + row < N) {
                if (rg == 0) { sA += v; qA += v * v; } else { sB += v; qB += v * v; }
            }
            acts[row * MSTR + col] = bf16r(v);
        }
    }
    __syncthreads();  // S3: output staged
    {
        int row = t >> 3, qo = t & 7;
        int gr = tileBase + row;
        if (gr < N) houtU4[(size_t)gr * 8 + qo] = actsU4[row * 9 + qo];
    }
    red[q][col] = sA;
    red[4 + q][col] = sB;
    __syncthreads();
    if (t < 64) {
        float S = 0.f;
        for (int i = 0; i < 8; i++) S += red[i][t];
        partS[blockIdx.x * 64 + t] = S;
    }
    __syncthreads();
    red[q][col] = qA;
    red[4 + q][col] = qB;
    __syncthreads();
    if (t < 64) {
        float S = 0.f;
        for (int i = 0; i < 8; i++) S += red[i][t];
        partQ[blockIdx.x * 64 + t] = S;
    }
}

// ---- bn_reduce v2: 64 blocks, block b reduces column b over nParts ----
__global__ __launch_bounds__(256) void bn_reduce(
    const float* __restrict__ partS, const float* __restrict__ partQ,
    float* __restrict__ bnsum, float* __restrict__ bnsq, int nParts) {
    __shared__ float rs[256], rq[256];
    int b = blockIdx.x, t = threadIdx.x;
    float S = 0.f, Q = 0.f;
    for (int p = t; p < nParts; p += 256) {
        S += partS[p * 64 + b];
        Q += partQ[p * 64 + b];
    }
    rs[t] = S; rq[t] = Q;
    __syncthreads();
    for (int off = 128; off > 0; off >>= 1) {
        if (t < off) { rs[t] += rs[t + off]; rq[t] += rq[t + off]; }
        __syncthreads();
    }
    if (t == 0) { bnsum[b] = rs[0]; bnsq[b] = rq[0]; }
}

// ---- BN apply + mean-pool + output matmul (batch sorted; zero atomics) ----
__device__ __forceinline__ int lowb(const int* __restrict__ a, int n, int v) {
    int lo = 0, hi = n;
    while (lo < hi) {
        int m = (lo + hi) >> 1;
        if (a[m] < v) lo = m + 1; else hi = m;
    }
    return lo;
}

__global__ __launch_bounds__(256) void bn_pool_out(
    const unsigned short* __restrict__ h, const int* __restrict__ batch,
    const float* __restrict__ bnsum, const float* __restrict__ bnsq,
    const float* __restrict__ gamma, const float* __restrict__ beta,
    const float* __restrict__ wout, const float* __restrict__ bout,
    float* __restrict__ out, int N) {
    __shared__ float sc[64], sh[64];
    __shared__ float part[4][64];
    __shared__ float gr[64];
    __shared__ int range[2];
    int g = blockIdx.x, t = threadIdx.x;
    if (t < 64) {
        float mu = bnsum[t] / (float)N;
        float var = bnsq[t] / (float)N - mu * mu;
        float s = gamma[t] * rsqrtf(var + 1e-5f);
        sc[t] = s;
        sh[t] = beta[t] - mu * s;
    }
    if (t == 64) range[0] = lowb(batch, N, g);
    if (t == 65) range[1] = lowb(batch, N, g + 1);
    __syncthreads();
    int s0 = range[0], s1 = range[1];
    int col = t & 63, ro = t >> 6;
    float acc = 0.f;
    for (int n = s0 + ro; n < s1; n += 4) {
        float v = __uint_as_float(((unsigned)h[(size_t)n * 64 + col]) << 16);
        acc += fmaxf(v * sc[col] + sh[col], 0.f);
    }
    part[ro][col] = acc;
    __syncthreads();
    if (t < 64) {
        float S = part[0][t] + part[1][t] + part[2][t] + part[3][t];
        float c = (float)(s1 - s0);
        gr[t] = (c > 0.f) ? S / c : 0.f;
    }
    __syncthreads();
    if (t < 64) {
        float a = bout[t];
        for (int f = 0; f < 64; f++) a += gr[f] * wout[f * 64 + t];
        out[g * 64 + t] = a;
    }
}

extern "C" void kernel_launch(void* const* d_in, const int* in_sizes, int n_in,
                              void* d_out, int out_size, void* d_ws, size_t ws_size,
                              hipStream_t stream) {
    const float* x     = (const float*)d_in[0];
    const int*   ei    = (const int*)d_in[1];
    const int*   batch = (const int*)d_in[2];
    const float* w1_0  = (const float*)d_in[3];
    const float* w1_r  = (const float*)d_in[4];
    const float* b1    = (const float*)d_in[5];
    const float* w2    = (const float*)d_in[6];
    const float* b2    = (const float*)d_in[7];
    const float* gamma = (const float*)d_in[8];
    const float* beta  = (const float*)d_in[9];
    const float* wout  = (const float*)d_in[10];
    const float* bout  = (const float*)d_in[11];
    float* out = (float*)d_out;

    const int N = in_sizes[2];               // 100000
    const int E = in_sizes[1] / 2;           // 3200000
    const int NB = (N + 127) >> 7;           // 782 buckets
    const int nblk = (E + CHUNK - 1) / CHUNK;// 391 scatter blocks
    const int nT32 = (N + 31) >> 5;          // 3125 layer tiles

    // Workspace (~60 MB)
    unsigned short* hbX = (unsigned short*)d_ws;             // N*64 bf16
    unsigned short* hbY = hbX + (size_t)N * 64;              // N*64 bf16
    int* bucketed2 = (int*)(hbY + (size_t)N * 64);           // nblk*CHUNK
    int* offsTab   = bucketed2 + (size_t)nblk * CHUNK;       // nblk*1025
    int* csrOut    = offsTab + (size_t)nblk * 1025;          // NB*CAP
    int* rowstart  = csrOut + (size_t)NB * CAP;              // N
    int* rowend    = rowstart + N;                           // N
    float* bnstats = (float*)(rowend + N);                   // 6*64
    float* partS   = bnstats + 384;                          // nT32*64
    float* partQ   = partS + (size_t)nT32 * 64;              // nT32*64
    unsigned short* w1T0 = (unsigned short*)(partQ + (size_t)nT32 * 64); // 64*32
    unsigned short* w1T  = w1T0 + 64 * 32;                   // 2*64*64
    unsigned short* w2T  = w1T + 2 * 64 * 64;                // 3*64*64

    const int* srcv = ei;
    const int* dstv = ei + E;

    prep_weights<<<48, 256, 0, stream>>>(w1_0, w1_r, w2, w1T0, w1T, w2T);

    // --- CSR build ---
    scatter_sort<<<nblk, 512, 0, stream>>>(srcv, dstv, bucketed2, offsTab, E);
    bucket_csr<<<NB, 256, 0, stream>>>(bucketed2, offsTab, csrOut, rowstart, rowend, N, nblk);

    // --- Layer 0 (fused agg3 + MLP) ---
    gin_layer<true><<<nT32, 256, 0, stream>>>(x, rowstart, rowend, csrOut,
                                              nullptr, nullptr, nullptr, nullptr,
                                              (const uint4*)w1T0, b1,
                                              (const uint4*)w2T, b2,
                                              (uint4*)hbX, partS, partQ, N);
    bn_reduce<<<64, 256, 0, stream>>>(partS, partQ, bnstats, bnstats + 64, nT32);

    // --- Layer 1 (fused BN0+agg + MLP) ---
    gin_layer<false><<<nT32, 256, 0, stream>>>(hbX, rowstart, rowend, csrOut,
                                               bnstats, bnstats + 64, gamma, beta,
                                               (const uint4*)w1T, b1 + 64,
                                               (const uint4*)(w2T + 4096), b2 + 64,
                                               (uint4*)hbY, partS, partQ, N);
    bn_reduce<<<64, 256, 0, stream>>>(partS, partQ, bnstats + 128, bnstats + 192, nT32);

    // --- Layer 2 (fused BN1+agg + MLP) ---
    gin_layer<false><<<nT32, 256, 0, stream>>>(hbY, rowstart, rowend, csrOut,
                                               bnstats + 128, bnstats + 192,
                                               gamma + 64, beta + 64,
                                               (const uint4*)(w1T + 4096), b1 + 128,
                                               (const uint4*)(w2T + 8192), b2 + 128,
                                               (uint4*)hbX, partS, partQ, N);
    bn_reduce<<<64, 256, 0, stream>>>(partS, partQ, bnstats + 256, bnstats + 320, nT32);

    // --- BN2 apply + pool + output matmul ---
    bn_pool_out<<<512, 256, 0, stream>>>(hbX, batch, bnstats + 256, bnstats + 320,
                                         gamma + 128, beta + 128, wout, bout, out, N);
}